// Round 2
// baseline (5502.019 us; speedup 1.0000x reference)
//
#include <hip/hip_runtime.h>
#include <stdint.h>

// Transformer-XL relative attention, f32 correctness-first baseline, round 2.
// L=qlen=klen=1024, BATCH=4, NH=16 heads, DH=64, DM=1024.
//
// rel_shift index map (verified on 2x2 toy):
//   t = j - i
//   BD[i,j] = BDp[i,   L-1+t]  if t <= 0      (BDp[i,c] = (q_i+v)·rh_c)
//           = 0                if t == 1
//           = BDp[i+1, t-2  ]  if t >= 2
// Along a diagonal t the same rh row is used -> stage a band of rh rows
// indexed by t, compute BDt[i'][tt] = qv_i' · band_tt as a GEMM, gather
// BD[i,j] = BDt[i + (t>=1)][tt], tt = jj-ii+TI-1.
//
// Round-2 change: mask dtype is detected at runtime (int32 / packed bool
// bytes / float32) from the first 4096 bytes, then staged per-block into LDS.
// Round-1 failure (absmax 0.94, batch-dependent) matches bool-uploaded-as-
// int32 read with 1-byte stride: batch 0 correct, batches 1-3 never masked.

#define L 1024
#define BATCH 4
#define NH 16
#define DH 64
#define DM 1024
#define TI 16          // i-rows per block
#define TJ 64          // j-tile
#define NTT 79         // TI + TJ - 1 band rows actually used
#define NTTP 80        // padded band rows
#define DHP 65         // pad to kill LDS bank conflicts on stride-64 rows
#define SCALE 0.125f   // 1/sqrt(64)
#define NEGINF (-3.402823466e38f)

// ---------------------------------------------------------------------------
// K1: rh[j, m] = sum_k r[j,k] * Wr[m,k] + br[m]
// ---------------------------------------------------------------------------
__global__ __launch_bounds__(256) void rh_gemm_kernel(
    const float* __restrict__ r, const float* __restrict__ Wr,
    const float* __restrict__ br, float* __restrict__ rh)
{
    __shared__ float As[16][65];   // [k][j-row]
    __shared__ float Bs[16][65];   // [k][m-col]
    const int j0 = blockIdx.x * 64;
    const int m0 = blockIdx.y * 64;
    const int tid = threadIdx.x;
    const int ty = tid >> 4, tx = tid & 15;
    float acc[4][4] = {};

    for (int k0 = 0; k0 < DM; k0 += 16) {
        const int row = tid >> 2, c4 = (tid & 3) << 2;
        float4 av = *(const float4*)(r  + (size_t)(j0 + row) * DM + k0 + c4);
        float4 bv = *(const float4*)(Wr + (size_t)(m0 + row) * DM + k0 + c4);
        __syncthreads();
        As[c4 + 0][row] = av.x; As[c4 + 1][row] = av.y;
        As[c4 + 2][row] = av.z; As[c4 + 3][row] = av.w;
        Bs[c4 + 0][row] = bv.x; Bs[c4 + 1][row] = bv.y;
        Bs[c4 + 2][row] = bv.z; Bs[c4 + 3][row] = bv.w;
        __syncthreads();
#pragma unroll
        for (int k = 0; k < 16; ++k) {
            float a[4], bb[4];
#pragma unroll
            for (int t = 0; t < 4; ++t) { a[t] = As[k][ty * 4 + t]; bb[t] = Bs[k][tx * 4 + t]; }
#pragma unroll
            for (int ii = 0; ii < 4; ++ii)
#pragma unroll
                for (int jj = 0; jj < 4; ++jj)
                    acc[ii][jj] = fmaf(a[ii], bb[jj], acc[ii][jj]);
        }
    }
#pragma unroll
    for (int ii = 0; ii < 4; ++ii) {
        const int row = j0 + ty * 4 + ii;
#pragma unroll
        for (int jj = 0; jj < 4; ++jj) {
            const int col = m0 + tx * 4 + jj;
            rh[(size_t)row * DM + col] = acc[ii][jj] + br[col];
        }
    }
}

// ---------------------------------------------------------------------------
// K2: fused rel-attention. Block = (i-tile of 16 rows, batch b), all 16 heads.
// ---------------------------------------------------------------------------
__global__ __launch_bounds__(256) void attn_kernel(
    const float* __restrict__ q, const float* __restrict__ Kg,
    const float* __restrict__ Vg, const unsigned char* __restrict__ maskp,
    const float* __restrict__ u, const float* __restrict__ v,
    const float* __restrict__ rh, float* __restrict__ out,
    float* __restrict__ wm_out)
{
    __shared__ float qu[TI][DHP];
    __shared__ float qv[TI + 1][DHP];
    __shared__ float Kt[TJ][DHP];
    __shared__ float Vt[TJ][DHP];
    __shared__ float band[NTTP][DHP];
    __shared__ float bdt[TI + 1][NTTP];
    __shared__ float St[TI][TJ + 1];
    __shared__ float stm[NH][TI];
    __shared__ float stl[NH][TI];
    __shared__ float wm[TI][L];          // head-mean weights, 64KB
    __shared__ unsigned char mblk[L];    // this batch's mask column
    __shared__ int mflags;

    const int i0 = blockIdx.x * TI;
    const int b  = blockIdx.y;
    const int tid = threadIdx.x;
    const int ty = tid >> 5;
    const int tx = tid & 31;
    const int r0 = 2 * ty;

    // ---- mask dtype detection on first 4096 bytes (safe for all layouts) --
    // word==0x3f800000 -> float32; nonzero byte at offset%4!=0 -> bool bytes;
    // else int32. P(misclassify) ~ 0 for a 10%-density 4096-elem mask.
    if (tid == 0) mflags = 0;
    __syncthreads();
    {
        int local = 0;
        for (int w = tid; w < 1024; w += 256) {
            const unsigned int word = ((const unsigned int*)maskp)[w];
            if (word == 0x3f800000u) local |= 1;
            else if (word & 0xffffff00u) local |= 2;
        }
        if (local) atomicOr(&mflags, local);
    }
    // zero the weight-mean accumulator meanwhile
    for (int idx = tid; idx < TI * L; idx += 256) ((float*)wm)[idx] = 0.f;
    __syncthreads();
    {
        const int mtype = (mflags & 1) ? 2 : ((mflags & 2) ? 1 : 0);
        for (int j = tid; j < L; j += 256) {
            bool mv;
            if (mtype == 2)      mv = ((const float*)maskp)[j * BATCH + b] != 0.f;
            else if (mtype == 1) mv = maskp[j * BATCH + b] != 0;
            else                 mv = ((const int*)maskp)[j * BATCH + b] != 0;
            mblk[j] = mv ? 1 : 0;
        }
    }
    // (first head's __syncthreads below covers mblk visibility)

    // ============================ PHASE 1: stats ===========================
    for (int n = 0; n < NH; ++n) {
        for (int idx = tid; idx < (TI + 1) * DH; idx += 256) {
            const int row = idx >> 6, d = idx & 63;
            const int gi = i0 + row;
            const float qval = (gi < L) ? q[((size_t)gi * BATCH + b) * DM + n * DH + d] : 0.f;
            qv[row][d] = qval + v[n * DH + d];
            if (row < TI) qu[row][d] = qval + u[n * DH + d];
        }
        if (tid < TI) { stm[n][tid] = NEGINF; stl[n][tid] = 0.f; }
        __syncthreads();

        for (int j0 = 0; j0 < L; j0 += TJ) {
            for (int idx = tid; idx < TJ * DH; idx += 256) {
                const int row = idx >> 6, d = idx & 63;
                Kt[row][d] = Kg[((size_t)(j0 + row) * BATCH + b) * DM + n * DH + d];
            }
            const int tmin = j0 - i0 - (TI - 1);
            for (int idx = tid; idx < NTTP * DH; idx += 256) {
                const int tt = idx >> 6, d = idx & 63;
                const int t = tmin + tt;
                float val = 0.f;
                if (t != 1) {
                    const int c = (t <= 0) ? (L - 1 + t) : (t - 2);
                    if (c >= 0 && c < L) val = rh[(size_t)c * DM + n * DH + d];
                }
                band[tt][d] = val;
            }
            __syncthreads();

            float ac[2][2] = {{0.f, 0.f}, {0.f, 0.f}};
            for (int d = 0; d < DH; ++d) {
                const float a0 = qu[r0][d], a1 = qu[r0 + 1][d];
                const float b0 = Kt[2 * tx][d], b1 = Kt[2 * tx + 1][d];
                ac[0][0] = fmaf(a0, b0, ac[0][0]); ac[0][1] = fmaf(a0, b1, ac[0][1]);
                ac[1][0] = fmaf(a1, b0, ac[1][0]); ac[1][1] = fmaf(a1, b1, ac[1][1]);
            }

            if (tid < 180) {
                const int g = tid / 20, tg = tid - 20 * g;
                const int ia = 2 * g;
                const int ib = (2 * g + 1 <= TI) ? (2 * g + 1) : TI;
                const int tt0 = 4 * tg;
                float aA[4] = {0, 0, 0, 0}, aB[4] = {0, 0, 0, 0};
                for (int d = 0; d < DH; ++d) {
                    const float qa = qv[ia][d], qb = qv[ib][d];
#pragma unroll
                    for (int t4 = 0; t4 < 4; ++t4) {
                        const float bv = band[tt0 + t4][d];
                        aA[t4] = fmaf(qa, bv, aA[t4]);
                        aB[t4] = fmaf(qb, bv, aB[t4]);
                    }
                }
#pragma unroll
                for (int t4 = 0; t4 < 4; ++t4) {
                    bdt[ia][tt0 + t4] = aA[t4];
                    bdt[ib][tt0 + t4] = aB[t4];
                }
            }
            __syncthreads();

            float sv[2][2];
#pragma unroll
            for (int rr = 0; rr < 2; ++rr) {
                const int ii = r0 + rr;
                const int gi = i0 + ii;
#pragma unroll
                for (int cc = 0; cc < 2; ++cc) {
                    const int jj = 2 * tx + cc;
                    const int gj = j0 + jj;
                    const int t = gj - gi;
                    const int tt = jj - ii + (TI - 1);
                    const int brow = ii + (t >= 1 ? 1 : 0);
                    float ss = (ac[rr][cc] + bdt[brow][tt]) * SCALE;
                    if (mblk[gj]) ss = -1e9f;
                    sv[rr][cc] = ss;
                }
            }
#pragma unroll
            for (int rr = 0; rr < 2; ++rr) {
                const int ii = r0 + rr;
                float mx = fmaxf(sv[rr][0], sv[rr][1]);
#pragma unroll
                for (int off = 16; off >= 1; off >>= 1)
                    mx = fmaxf(mx, __shfl_xor(mx, off, 32));
                const float mold = stm[n][ii];
                const float mnew = fmaxf(mold, mx);
                float e = __expf(sv[rr][0] - mnew) + __expf(sv[rr][1] - mnew);
#pragma unroll
                for (int off = 16; off >= 1; off >>= 1)
                    e += __shfl_xor(e, off, 32);
                if (tx == 0) {
                    stl[n][ii] = stl[n][ii] * __expf(mold - mnew) + e;
                    stm[n][ii] = mnew;
                }
            }
            __syncthreads();
        }
    }

    // ====================== PHASE 2: weights + outputs =====================
    for (int n = 0; n < NH; ++n) {
        for (int idx = tid; idx < (TI + 1) * DH; idx += 256) {
            const int row = idx >> 6, d = idx & 63;
            const int gi = i0 + row;
            const float qval = (gi < L) ? q[((size_t)gi * BATCH + b) * DM + n * DH + d] : 0.f;
            qv[row][d] = qval + v[n * DH + d];
            if (row < TI) qu[row][d] = qval + u[n * DH + d];
        }
        __syncthreads();
        float oacc[2][2] = {{0.f, 0.f}, {0.f, 0.f}};

        for (int j0 = 0; j0 < L; j0 += TJ) {
            for (int idx = tid; idx < TJ * DH; idx += 256) {
                const int row = idx >> 6, d = idx & 63;
                Kt[row][d] = Kg[((size_t)(j0 + row) * BATCH + b) * DM + n * DH + d];
                Vt[row][d] = Vg[((size_t)(j0 + row) * BATCH + b) * DM + n * DH + d];
            }
            const int tmin = j0 - i0 - (TI - 1);
            for (int idx = tid; idx < NTTP * DH; idx += 256) {
                const int tt = idx >> 6, d = idx & 63;
                const int t = tmin + tt;
                float val = 0.f;
                if (t != 1) {
                    const int c = (t <= 0) ? (L - 1 + t) : (t - 2);
                    if (c >= 0 && c < L) val = rh[(size_t)c * DM + n * DH + d];
                }
                band[tt][d] = val;
            }
            __syncthreads();

            float ac[2][2] = {{0.f, 0.f}, {0.f, 0.f}};
            for (int d = 0; d < DH; ++d) {
                const float a0 = qu[r0][d], a1 = qu[r0 + 1][d];
                const float b0 = Kt[2 * tx][d], b1 = Kt[2 * tx + 1][d];
                ac[0][0] = fmaf(a0, b0, ac[0][0]); ac[0][1] = fmaf(a0, b1, ac[0][1]);
                ac[1][0] = fmaf(a1, b0, ac[1][0]); ac[1][1] = fmaf(a1, b1, ac[1][1]);
            }
            if (tid < 180) {
                const int g = tid / 20, tg = tid - 20 * g;
                const int ia = 2 * g;
                const int ib = (2 * g + 1 <= TI) ? (2 * g + 1) : TI;
                const int tt0 = 4 * tg;
                float aA[4] = {0, 0, 0, 0}, aB[4] = {0, 0, 0, 0};
                for (int d = 0; d < DH; ++d) {
                    const float qa = qv[ia][d], qb = qv[ib][d];
#pragma unroll
                    for (int t4 = 0; t4 < 4; ++t4) {
                        const float bv = band[tt0 + t4][d];
                        aA[t4] = fmaf(qa, bv, aA[t4]);
                        aB[t4] = fmaf(qb, bv, aB[t4]);
                    }
                }
#pragma unroll
                for (int t4 = 0; t4 < 4; ++t4) {
                    bdt[ia][tt0 + t4] = aA[t4];
                    bdt[ib][tt0 + t4] = aB[t4];
                }
            }
            __syncthreads();

#pragma unroll
            for (int rr = 0; rr < 2; ++rr) {
                const int ii = r0 + rr;
                const int gi = i0 + ii;
                const float mrow = stm[n][ii];
                const float rinv = 1.f / stl[n][ii];
#pragma unroll
                for (int cc = 0; cc < 2; ++cc) {
                    const int jj = 2 * tx + cc;
                    const int gj = j0 + jj;
                    const int t = gj - gi;
                    const int tt = jj - ii + (TI - 1);
                    const int brow = ii + (t >= 1 ? 1 : 0);
                    float ss = (ac[rr][cc] + bdt[brow][tt]) * SCALE;
                    if (mblk[gj]) ss = -1e9f;
                    const float w = __expf(ss - mrow) * rinv;
                    St[ii][jj] = w;
                    wm[ii][gj] += w * (1.f / NH);   // exclusive (ii,gj) owner
                }
            }
            __syncthreads();

            for (int jj = 0; jj < TJ; ++jj) {
                const float w0 = St[r0][jj], w1 = St[r0 + 1][jj];
                const float v0 = Vt[jj][2 * tx], v1 = Vt[jj][2 * tx + 1];
                oacc[0][0] = fmaf(w0, v0, oacc[0][0]);
                oacc[0][1] = fmaf(w0, v1, oacc[0][1]);
                oacc[1][0] = fmaf(w1, v0, oacc[1][0]);
                oacc[1][1] = fmaf(w1, v1, oacc[1][1]);
            }
            __syncthreads();
        }
#pragma unroll
        for (int rr = 0; rr < 2; ++rr)
#pragma unroll
            for (int cc = 0; cc < 2; ++cc)
                out[((size_t)(i0 + r0 + rr) * BATCH + b) * DM + n * DH + 2 * tx + cc] =
                    oacc[rr][cc];
    }

    // weight-mean writeout: wm_out[(i*L + j)*BATCH + b]
    for (int idx = tid; idx < TI * L; idx += 256) {
        const int row = idx >> 10, j = idx & 1023;
        wm_out[((size_t)(i0 + row) * L + j) * BATCH + b] = wm[row][j];
    }
}

// ---------------------------------------------------------------------------
extern "C" void kernel_launch(void* const* d_in, const int* in_sizes, int n_in,
                              void* d_out, int out_size, void* d_ws, size_t ws_size,
                              hipStream_t stream)
{
    (void)in_sizes; (void)n_in; (void)out_size; (void)ws_size;
    const float* q   = (const float*)d_in[0];
    const float* K   = (const float*)d_in[1];
    const float* V   = (const float*)d_in[2];
    const unsigned char* mask = (const unsigned char*)d_in[3]; // dtype detected on device
    const float* r   = (const float*)d_in[4];
    const float* u   = (const float*)d_in[5];
    const float* v   = (const float*)d_in[6];
    const float* Wr  = (const float*)d_in[7];
    const float* br  = (const float*)d_in[8];

    float* out = (float*)d_out;                       // (1024, 4, 1024)
    float* wm  = out + (size_t)L * BATCH * DM;        // (1024, 1024, 4)
    float* rh  = (float*)d_ws;                        // (1024, 1024) = 4 MB

    rh_gemm_kernel<<<dim3(DM / 64, DM / 64), 256, 0, stream>>>(r, Wr, br, rh);
    attn_kernel<<<dim3(L / TI, BATCH), 256, 0, stream>>>(q, K, V, mask, u, v, rh,
                                                         out, wm);
}

// Round 3
// 1308.533 us; speedup vs baseline: 4.2047x; 4.2047x over previous
//
#include <hip/hip_runtime.h>
#include <stdint.h>

// Transformer-XL relative attention, round 3: bf16 MFMA rewrite.
// L=qlen=klen=1024, BATCH=4, NH=16, DH=64, DM=1024.
//
// Per block (i-tile of 16 rows, batch b), all 16 heads serially:
//   1. BDp[i][c] = (q_i+v)·rh_c for i=0..16, c=0..1023 (MFMA rows 0-15, VALU row 16)
//   2. j-loop: AC = (q+u)K^T via MFMA; S = (AC + gather(BDp))/8; mask; w=exp(s)
//      (no max subtraction: s ~ N(0,1.4), masked -> exp(-1e9)=0 exactly);
//      W stored bf16 in LDS; PV via MFMA (V staged transposed).
//   3. denom reduce -> out = PV/l; wm_out (+)= W/(l*16)  (global RMW, block-exclusive).
//
// rel_shift map (HW-verified round 2): t=j-i; BD= t==1?0 : BDp[i+(t>=1)][t<=0?1023+t:t-2].
// MFMA frag convention (m89/m91-verified): A/B: row|col=lane&15, k=(lane>>4)*8+e
// contiguous (b128 reads); D: col=lane&15, row=(lane>>4)*4+reg.

#define L 1024
#define BATCH 4
#define NH 16
#define DH 64
#define DM 1024
#define TI 16
#define TJ 128
#define NJT (L / TJ)        // 8
#define BDP_STRIDE 1028     // f32 elems per BDp row
#define WF_STRIDE 1032      // bf16 elems per Wf row
#define SCALE 0.125f

typedef __attribute__((ext_vector_type(8))) short short8;
typedef __attribute__((ext_vector_type(4))) float f32x4;

static __device__ __forceinline__ unsigned short f2bf(float f) {
    union { float f; unsigned int u; } x; x.f = f;
    unsigned int r = (x.u + 0x7fffu + ((x.u >> 16) & 1u)) >> 16;  // RNE
    return (unsigned short)r;
}
static __device__ __forceinline__ float bf2f(unsigned short h) {
    union { unsigned int u; float f; } x; x.u = ((unsigned int)h) << 16;
    return x.f;
}
static __device__ __forceinline__ unsigned short* usp(void* base, int byteoff) {
    return (unsigned short*)((char*)base + byteoff);
}
static __device__ __forceinline__ short8 ld8(const void* base, int byteoff) {
    return *(const short8*)((const char*)base + byteoff);
}
// swizzles: XOR within a row keeps b128 alignment, kills stride-128/256 conflicts
#define SW128(row, colByte) ((((row) * 128) + (colByte)) ^ (((row) & 7) << 4))
#define SWV(d, colByte)     ((((d) * 256) + (colByte)) ^ (((d) & 15) << 4))

// ---------------------------------------------------------------------------
// K1: rh[j,m] = sum_k r[j,k]*Wr[m,k] + br[m]   (f32, unchanged from round 2)
// ---------------------------------------------------------------------------
__global__ __launch_bounds__(256) void rh_gemm_kernel(
    const float* __restrict__ r, const float* __restrict__ Wr,
    const float* __restrict__ br, float* __restrict__ rh)
{
    __shared__ float As[16][65];
    __shared__ float Bs[16][65];
    const int j0 = blockIdx.x * 64;
    const int m0 = blockIdx.y * 64;
    const int tid = threadIdx.x;
    const int ty = tid >> 4, tx = tid & 15;
    float acc[4][4] = {};

    for (int k0 = 0; k0 < DM; k0 += 16) {
        const int row = tid >> 2, c4 = (tid & 3) << 2;
        float4 av = *(const float4*)(r  + (size_t)(j0 + row) * DM + k0 + c4);
        float4 bv = *(const float4*)(Wr + (size_t)(m0 + row) * DM + k0 + c4);
        __syncthreads();
        As[c4 + 0][row] = av.x; As[c4 + 1][row] = av.y;
        As[c4 + 2][row] = av.z; As[c4 + 3][row] = av.w;
        Bs[c4 + 0][row] = bv.x; Bs[c4 + 1][row] = bv.y;
        Bs[c4 + 2][row] = bv.z; Bs[c4 + 3][row] = bv.w;
        __syncthreads();
#pragma unroll
        for (int k = 0; k < 16; ++k) {
            float a[4], bb[4];
#pragma unroll
            for (int t = 0; t < 4; ++t) { a[t] = As[k][ty * 4 + t]; bb[t] = Bs[k][tx * 4 + t]; }
#pragma unroll
            for (int ii = 0; ii < 4; ++ii)
#pragma unroll
                for (int jj = 0; jj < 4; ++jj)
                    acc[ii][jj] = fmaf(a[ii], bb[jj], acc[ii][jj]);
        }
    }
#pragma unroll
    for (int ii = 0; ii < 4; ++ii) {
        const int row = j0 + ty * 4 + ii;
#pragma unroll
        for (int jj = 0; jj < 4; ++jj) {
            const int col = m0 + tx * 4 + jj;
            rh[(size_t)row * DM + col] = acc[ii][jj] + br[col];
        }
    }
}

// ---------------------------------------------------------------------------
// K2: fused rel-attention, MFMA.
// ---------------------------------------------------------------------------
__global__ __launch_bounds__(256) void attn_kernel(
    const float* __restrict__ q, const float* __restrict__ Kg,
    const float* __restrict__ Vg, const unsigned char* __restrict__ maskp,
    const float* __restrict__ uu, const float* __restrict__ vv,
    const float* __restrict__ rh, float* __restrict__ out,
    float* __restrict__ wm_out)
{
    __shared__ unsigned short QU[16 * 64];        // (q+u) bf16, swizzled
    __shared__ unsigned short QV[17 * 64];        // (q+v) bf16, swizzled
    __shared__ unsigned short KR[TJ * 64];        // RH tile / K tile union
    __shared__ unsigned short VT[64 * TJ];        // V transposed [d][j]
    __shared__ float BDp[17 * BDP_STRIDE];        // 69.9 KB
    __shared__ unsigned short Wf[16 * WF_STRIDE]; // unnormalized weights, 33 KB
    __shared__ unsigned char mblk[L];
    __shared__ float denomP[4][16];
    __shared__ float rdenom[16];
    __shared__ int mflags;

    const int i0 = blockIdx.x * TI;
    const int b  = blockIdx.y;
    const int tid = threadIdx.x;
    const int w = tid >> 6;       // wave 0..3
    const int lane = tid & 63;
    const int lr = lane & 15;
    const int lg = lane >> 4;

    // ---- mask dtype detection + staging (verified round 2) ----------------
    if (tid == 0) mflags = 0;
    __syncthreads();
    {
        int local = 0;
        for (int ww = tid; ww < 1024; ww += 256) {
            const unsigned int word = ((const unsigned int*)maskp)[ww];
            if (word == 0x3f800000u) local |= 1;
            else if (word & 0xffffff00u) local |= 2;
        }
        if (local) atomicOr(&mflags, local);
    }
    __syncthreads();
    {
        const int mtype = (mflags & 1) ? 2 : ((mflags & 2) ? 1 : 0);
        for (int j = tid; j < L; j += 256) {
            bool mv;
            if (mtype == 2)      mv = ((const float*)maskp)[j * BATCH + b] != 0.f;
            else if (mtype == 1) mv = maskp[j * BATCH + b] != 0;
            else                 mv = ((const int*)maskp)[j * BATCH + b] != 0;
            mblk[j] = mv ? 1 : 0;
        }
    }
    __syncthreads();

    for (int n = 0; n < NH; ++n) {
        __syncthreads();  // fence vs previous head's Wf/rdenom readers

        // ---- stage QU (16x64) and QV (17x64) as bf16, swizzled ----
        for (int idx = tid; idx < 17 * 64; idx += 256) {
            int row = idx >> 6, d = idx & 63;
            int gi = i0 + row;
            float qval = (gi < L) ? q[((size_t)gi * BATCH + b) * DM + n * DH + d] : 0.f;
            *usp(QV, SW128(row, d * 2)) = f2bf(qval + vv[n * DH + d]);
            if (row < 16) *usp(QU, SW128(row, d * 2)) = f2bf(qval + uu[n * DH + d]);
        }

        // ---- BDp: rows 0-15 via MFMA over c-tiles; row 16 via VALU ----
        for (int ct = 0; ct < NJT; ++ct) {
            int c0 = ct * TJ;
            __syncthreads();  // prev KR readers done (also covers QU/QV writes)
            for (int e4 = tid; e4 < TJ * 16; e4 += 256) {
                int cr = e4 >> 4, d4 = (e4 & 15) * 4;
                const float4 rv = *(const float4*)(rh + (size_t)(c0 + cr) * DM + n * DH + d4);
                unsigned short* p = usp(KR, SW128(cr, d4 * 2));
                p[0] = f2bf(rv.x); p[1] = f2bf(rv.y); p[2] = f2bf(rv.z); p[3] = f2bf(rv.w);
            }
            __syncthreads();
#pragma unroll
            for (int ch = 0; ch < 2; ++ch) {
                int ccol = w * 32 + ch * 16 + lr;
                f32x4 acc = {0.f, 0.f, 0.f, 0.f};
#pragma unroll
                for (int kh = 0; kh < 2; ++kh) {
                    short8 a  = ld8(QV, SW128(lr,   (kh * 32 + lg * 8) * 2));
                    short8 bb = ld8(KR, SW128(ccol, (kh * 32 + lg * 8) * 2));
                    acc = __builtin_amdgcn_mfma_f32_16x16x32_bf16(a, bb, acc, 0, 0, 0);
                }
#pragma unroll
                for (int r2 = 0; r2 < 4; ++r2)
                    BDp[(lg * 4 + r2) * BDP_STRIDE + c0 + ccol] = acc[r2];
            }
            {   // row 16: 2 threads per column, 32 k each
                int col = tid >> 1, kq = (tid & 1) * 32;
                float s16 = 0.f;
                for (int kk = 0; kk < 32; kk += 8) {
                    short8 qa = ld8(QV, SW128(16,  (kq + kk) * 2));
                    short8 ra = ld8(KR, SW128(col, (kq + kk) * 2));
#pragma unroll
                    for (int e = 0; e < 8; ++e)
                        s16 = fmaf(bf2f((unsigned short)qa[e]), bf2f((unsigned short)ra[e]), s16);
                }
                s16 += __shfl_xor(s16, 1);
                if (!(tid & 1)) BDp[16 * BDP_STRIDE + c0 + col] = s16;
            }
        }

        // ---- j-loop: AC, S, W, PV ----
        f32x4 pv = {0.f, 0.f, 0.f, 0.f};
        float dl[4] = {0.f, 0.f, 0.f, 0.f};
        for (int jt = 0; jt < NJT; ++jt) {
            int j0 = jt * TJ;
            __syncthreads();  // prior KR/VT readers done
            for (int e4 = tid; e4 < TJ * 16; e4 += 256) {
                int jr = e4 >> 4, d4 = (e4 & 15) * 4;
                const float4 kv = *(const float4*)(Kg + ((size_t)(j0 + jr) * BATCH + b) * DM + n * DH + d4);
                unsigned short* p = usp(KR, SW128(jr, d4 * 2));
                p[0] = f2bf(kv.x); p[1] = f2bf(kv.y); p[2] = f2bf(kv.z); p[3] = f2bf(kv.w);
                const float4 vv4 = *(const float4*)(Vg + ((size_t)(j0 + jr) * BATCH + b) * DM + n * DH + d4);
                *usp(VT, SWV(d4 + 0, jr * 2)) = f2bf(vv4.x);
                *usp(VT, SWV(d4 + 1, jr * 2)) = f2bf(vv4.y);
                *usp(VT, SWV(d4 + 2, jr * 2)) = f2bf(vv4.z);
                *usp(VT, SWV(d4 + 3, jr * 2)) = f2bf(vv4.w);
            }
            __syncthreads();
#pragma unroll
            for (int ch = 0; ch < 2; ++ch) {
                int jloc = w * 32 + ch * 16 + lr;
                int gj = j0 + jloc;
                f32x4 acc = {0.f, 0.f, 0.f, 0.f};
#pragma unroll
                for (int kh = 0; kh < 2; ++kh) {
                    short8 a  = ld8(QU, SW128(lr,   (kh * 32 + lg * 8) * 2));
                    short8 bb = ld8(KR, SW128(jloc, (kh * 32 + lg * 8) * 2));
                    acc = __builtin_amdgcn_mfma_f32_16x16x32_bf16(a, bb, acc, 0, 0, 0);
                }
#pragma unroll
                for (int r2 = 0; r2 < 4; ++r2) {
                    int il = lg * 4 + r2;
                    int gi = i0 + il;
                    int t = gj - gi;
                    float bd = 0.f;
                    if (t != 1) {
                        int c  = (t <= 0) ? (L - 1 + t) : (t - 2);
                        int br = il + (t >= 1 ? 1 : 0);
                        bd = BDp[br * BDP_STRIDE + c];
                    }
                    float s = (acc[r2] + bd) * SCALE;
                    if (mblk[gj]) s = -1e9f;
                    float wgt = __expf(fminf(s, 80.f));
                    dl[r2] += wgt;
                    Wf[il * WF_STRIDE + gj] = f2bf(wgt);
                }
            }
            __syncthreads();  // Wf tile visible to all waves
#pragma unroll
            for (int kh = 0; kh < 4; ++kh) {
                short8 a  = ld8(Wf, (lr * WF_STRIDE + j0 + kh * 32 + lg * 8) * 2);
                short8 bb = ld8(VT, SWV(w * 16 + lr, (kh * 32 + lg * 8) * 2));
                pv = __builtin_amdgcn_mfma_f32_16x16x32_bf16(a, bb, pv, 0, 0, 0);
            }
        }

        // ---- denominators ----
#pragma unroll
        for (int r2 = 0; r2 < 4; ++r2) {
            float d = dl[r2];
            d += __shfl_xor(d, 1); d += __shfl_xor(d, 2);
            d += __shfl_xor(d, 4); d += __shfl_xor(d, 8);
            if (lr == 0) denomP[w][lg * 4 + r2] = d;
        }
        __syncthreads();
        if (tid < 16)
            rdenom[tid] = 1.f / (denomP[0][tid] + denomP[1][tid] + denomP[2][tid] + denomP[3][tid]);
        __syncthreads();

        // ---- out = PV / l ----
#pragma unroll
        for (int r2 = 0; r2 < 4; ++r2) {
            int il = lg * 4 + r2;
            out[((size_t)(i0 + il) * BATCH + b) * DM + n * DH + w * 16 + lr] = pv[r2] * rdenom[il];
        }

        // ---- wm_out (+)= W/(l*NH): block-exclusive region, '=' on head 0 ----
        for (int e = tid; e < 16 * 1024; e += 256) {
            int il = e >> 10, j = e & 1023;
            float val = bf2f(Wf[il * WF_STRIDE + j]) * rdenom[il] * (1.f / 16.f);
            size_t o = ((size_t)(i0 + il) * L + j) * BATCH + b;
            if (n == 0) wm_out[o] = val;
            else        wm_out[o] += val;
        }
    }
}

// ---------------------------------------------------------------------------
extern "C" void kernel_launch(void* const* d_in, const int* in_sizes, int n_in,
                              void* d_out, int out_size, void* d_ws, size_t ws_size,
                              hipStream_t stream)
{
    (void)in_sizes; (void)n_in; (void)out_size; (void)ws_size;
    const float* q   = (const float*)d_in[0];
    const float* K   = (const float*)d_in[1];
    const float* V   = (const float*)d_in[2];
    const unsigned char* mask = (const unsigned char*)d_in[3];
    const float* r   = (const float*)d_in[4];
    const float* u   = (const float*)d_in[5];
    const float* v   = (const float*)d_in[6];
    const float* Wr  = (const float*)d_in[7];
    const float* br  = (const float*)d_in[8];

    float* out = (float*)d_out;                    // (1024, 4, 1024)
    float* wm  = out + (size_t)L * BATCH * DM;     // (1024, 1024, 4)
    float* rh  = (float*)d_ws;                     // (1024, 1024) f32, 4 MB

    rh_gemm_kernel<<<dim3(DM / 64, DM / 64), 256, 0, stream>>>(r, Wr, br, rh);
    attn_kernel<<<dim3(L / TI, BATCH), 256, 0, stream>>>(q, K, V, mask, u, v, rh,
                                                         out, wm);
}

// Round 4
// 1026.677 us; speedup vs baseline: 5.3591x; 1.2745x over previous
//
#include <hip/hip_runtime.h>
#include <hip/hip_fp16.h>
#include <stdint.h>

// Transformer-XL relative attention, round 4: head-parallel MFMA.
// L=qlen=klen=1024, BATCH=4, NH=16, DH=64, DM=1024.
//
// Grid = (i-tile 16 rows) x batch x head = 64*4*16 = 4096 blocks, 256 thr.
// Per block: BDp[i][c] = (q_i+v)·rh_c (fp16 in LDS, 17 rows), then 16 j-tiles:
// AC MFMA (B direct from global bf16 K), S = (AC + relshift-gather(BDp))/8,
// mask, w = exp(s) (no max-sub; masked -> exp(-1e9)=0 exactly), PV MFMA
// (B direct from pre-transposed global bf16 V). wm_out = memset(0) +
// atomicAdd of w*rdenom/16 (per-head W kept in 64 static registers).
//
// rel_shift map (HW-verified rounds 2-3): t=j-i;
//   BD = (t==1) ? 0 : BDp[i + (t>=1)][ t<=0 ? 1023+t : t-2 ].
// MFMA frag convention (verified round 3): A/B row|col=lane&15,
// k=(lane>>4)*8+e contiguous; D col=lane&15, row=(lane>>4)*4+reg.

#define L 1024
#define BATCH 4
#define NH 16
#define DH 64
#define DM 1024
#define TI 16
#define NJT 16
#define BDP_ST 1032     // fp16 elems per BDp row (pad: 2064B stride, +4 banks)
#define SCALE 0.125f

typedef __attribute__((ext_vector_type(8))) short short8;
typedef __attribute__((ext_vector_type(4))) float f32x4;

static __device__ __forceinline__ unsigned short f2bf(float f) {
    union { float f; unsigned int u; } x; x.f = f;
    return (unsigned short)((x.u + 0x7fffu + ((x.u >> 16) & 1u)) >> 16);  // RNE
}
static __device__ __forceinline__ float bf2f(unsigned short h) {
    union { unsigned int u; float f; } x; x.u = ((unsigned int)h) << 16;
    return x.f;
}
static __device__ __forceinline__ unsigned short f2h(float f) {
    __half h = __float2half(f);
    union { __half h; unsigned short s; } x; x.h = h; return x.s;
}
static __device__ __forceinline__ float h2f(unsigned short s) {
    union { __half h; unsigned short s; } x; x.s = s; return __half2float(x.h);
}
static __device__ __forceinline__ unsigned short* usp(void* base, int byteoff) {
    return (unsigned short*)((char*)base + byteoff);
}
static __device__ __forceinline__ short8 ld8(const void* base, int byteoff) {
    return *(const short8*)((const char*)base + byteoff);
}
#define SW128(row, colByte) ((((row) * 128) + (colByte)) ^ (((row) & 7) << 4))

// ---------------------------------------------------------------------------
// K1: rh[c,m] = sum_k r[c,k]*Wr[m,k] + br[m]; writes bf16 [n][c][d] (MODE0)
// or f32 [c][m] (MODE1 fallback).
// ---------------------------------------------------------------------------
__global__ __launch_bounds__(256) void rh_gemm_kernel(
    const float* __restrict__ r, const float* __restrict__ Wr,
    const float* __restrict__ br, float* __restrict__ rhf,
    unsigned short* __restrict__ rhb, int bfmode)
{
    __shared__ float As[16][65];
    __shared__ float Bs[16][65];
    const int j0 = blockIdx.x * 64;
    const int m0 = blockIdx.y * 64;
    const int tid = threadIdx.x;
    const int ty = tid >> 4, tx = tid & 15;
    float acc[4][4] = {};

    for (int k0 = 0; k0 < DM; k0 += 16) {
        const int row = tid >> 2, c4 = (tid & 3) << 2;
        float4 av = *(const float4*)(r  + (size_t)(j0 + row) * DM + k0 + c4);
        float4 bv = *(const float4*)(Wr + (size_t)(m0 + row) * DM + k0 + c4);
        __syncthreads();
        As[c4 + 0][row] = av.x; As[c4 + 1][row] = av.y;
        As[c4 + 2][row] = av.z; As[c4 + 3][row] = av.w;
        Bs[c4 + 0][row] = bv.x; Bs[c4 + 1][row] = bv.y;
        Bs[c4 + 2][row] = bv.z; Bs[c4 + 3][row] = bv.w;
        __syncthreads();
#pragma unroll
        for (int k = 0; k < 16; ++k) {
            float a[4], bb[4];
#pragma unroll
            for (int t = 0; t < 4; ++t) { a[t] = As[k][ty * 4 + t]; bb[t] = Bs[k][tx * 4 + t]; }
#pragma unroll
            for (int ii = 0; ii < 4; ++ii)
#pragma unroll
                for (int jj = 0; jj < 4; ++jj)
                    acc[ii][jj] = fmaf(a[ii], bb[jj], acc[ii][jj]);
        }
    }
#pragma unroll
    for (int ii = 0; ii < 4; ++ii) {
        const int row = j0 + ty * 4 + ii;
#pragma unroll
        for (int jj = 0; jj < 4; ++jj) {
            const int col = m0 + tx * 4 + jj;
            const float val = acc[ii][jj] + br[col];
            if (bfmode)
                rhb[(((size_t)(col >> 6)) * L + row) * DH + (col & 63)] = f2bf(val);
            else
                rhf[(size_t)row * DM + col] = val;
        }
    }
}

// ---------------------------------------------------------------------------
// Prepass: K f32[j][b][m] -> bf16 Kbf[b][n][j][d]; V -> bf16 Vtb[b][n][d][j].
// Grid (16 j-tiles, 4 b, 16 n), 256 threads.
// ---------------------------------------------------------------------------
__global__ __launch_bounds__(256) void prepass_kernel(
    const float* __restrict__ Kg, const float* __restrict__ Vg,
    unsigned short* __restrict__ Kbf, unsigned short* __restrict__ Vtb)
{
    __shared__ unsigned short tile[64][80];   // [d][j], rows 160B (16B-aligned)
    const int j0 = blockIdx.x * 64;
    const int b = blockIdx.y, n = blockIdx.z;
    const int bn = b * NH + n;
    const int tid = threadIdx.x;

    for (int idx = tid; idx < 64 * 16; idx += 256) {
        const int jr = idx >> 4, s4 = (idx & 15) * 4;
        const size_t src = ((size_t)(j0 + jr) * BATCH + b) * DM + n * DH + s4;
        float4 kv = *(const float4*)(Kg + src);
        ushort4 o;
        o.x = f2bf(kv.x); o.y = f2bf(kv.y); o.z = f2bf(kv.z); o.w = f2bf(kv.w);
        *(ushort4*)(Kbf + ((size_t)bn * L + j0 + jr) * DH + s4) = o;
        float4 vv4 = *(const float4*)(Vg + src);
        tile[s4 + 0][jr] = f2bf(vv4.x); tile[s4 + 1][jr] = f2bf(vv4.y);
        tile[s4 + 2][jr] = f2bf(vv4.z); tile[s4 + 3][jr] = f2bf(vv4.w);
    }
    __syncthreads();
    for (int idx = tid; idx < 64 * 8; idx += 256) {
        const int d = idx >> 3, p8 = (idx & 7) * 8;
        short8 o = *(const short8*)&tile[d][p8];
        *(short8*)(Vtb + ((size_t)bn * DH + d) * L + j0 + p8) = o;
    }
}

// ---------------------------------------------------------------------------
// K2: fused rel-attention, one head per block.
// MODE 0: bf16 prepassed inputs, MFMA B-frags direct from global.
// MODE 1: f32 inputs, per-tile LDS convert staging (fallback).
// ---------------------------------------------------------------------------
template<int MODE>
__global__ __launch_bounds__(256, 2) void attn_kernel(
    const float* __restrict__ q,
    const void* __restrict__ Kp, const void* __restrict__ Vp,
    const unsigned char* __restrict__ maskp,
    const float* __restrict__ uu, const float* __restrict__ vvp,
    const void* __restrict__ rhp,
    float* __restrict__ out, float* __restrict__ wm_out)
{
    __shared__ unsigned short QU[16 * 64];                    // SW128
    __shared__ unsigned short QV[17 * 64];                    // SW128
    __shared__ unsigned short KR[(MODE == 1) ? 64 * 64 : 8];  // MODE1 staging
    __shared__ unsigned short VT[(MODE == 1) ? 64 * 64 : 8];
    __shared__ unsigned short BDp[17 * BDP_ST];               // fp16, linear
    __shared__ unsigned short Wt[16 * 64];                    // SW128
    __shared__ unsigned char mblk[L];
    __shared__ float denomP[4][16];
    __shared__ float rdenom[16];
    __shared__ int mflags;

    const int i0 = blockIdx.x * TI;
    const int b  = blockIdx.y;
    const int n  = blockIdx.z;
    const int bn = b * NH + n;
    const int tid = threadIdx.x;
    const int w = tid >> 6, lane = tid & 63, lr = lane & 15, lg = lane >> 4;

    const unsigned short* Kbf = (const unsigned short*)Kp;
    const unsigned short* Vtb = (const unsigned short*)Vp;
    const unsigned short* rhb = (const unsigned short*)rhp;
    const float* Kg  = (const float*)Kp;
    const float* Vg  = (const float*)Vp;
    const float* rhf = (const float*)rhp;

    // ---- mask dtype detection + staging (verified round 2) ----
    if (tid == 0) mflags = 0;
    __syncthreads();
    {
        int local = 0;
        for (int ww = tid; ww < 1024; ww += 256) {
            const unsigned int word = ((const unsigned int*)maskp)[ww];
            if (word == 0x3f800000u) local |= 1;
            else if (word & 0xffffff00u) local |= 2;
        }
        if (local) atomicOr(&mflags, local);
    }
    __syncthreads();
    {
        const int mtype = (mflags & 1) ? 2 : ((mflags & 2) ? 1 : 0);
        for (int j = tid; j < L; j += 256) {
            bool mv;
            if (mtype == 2)      mv = ((const float*)maskp)[j * BATCH + b] != 0.f;
            else if (mtype == 1) mv = maskp[j * BATCH + b] != 0;
            else                 mv = ((const int*)maskp)[j * BATCH + b] != 0;
            mblk[j] = mv ? 1 : 0;
        }
    }
    // ---- stage QU (16x64), QV (17x64) bf16 swizzled ----
    for (int idx = tid; idx < 17 * 64; idx += 256) {
        const int row = idx >> 6, d = idx & 63;
        const int gi = i0 + row;
        const float qval = (gi < L) ? q[((size_t)gi * BATCH + b) * DM + n * DH + d] : 0.f;
        *usp(QV, SW128(row, d * 2)) = f2bf(qval + vvp[n * DH + d]);
        if (row < 16) *usp(QU, SW128(row, d * 2)) = f2bf(qval + uu[n * DH + d]);
    }
    __syncthreads();

    // ================= BDp build: 16 c-tiles of 64 =================
    for (int ct = 0; ct < 16; ++ct) {
        const int c0 = ct * 64;
        if constexpr (MODE == 1) {
            __syncthreads();   // prev tile's readers done
            for (int idx = tid; idx < 64 * 16; idx += 256) {
                const int cr = idx >> 4, d4 = (idx & 15) * 4;
                float4 rv = *(const float4*)(rhf + (size_t)(c0 + cr) * DM + n * DH + d4);
                unsigned short* p = usp(KR, SW128(cr, d4 * 2));
                p[0] = f2bf(rv.x); p[1] = f2bf(rv.y); p[2] = f2bf(rv.z); p[3] = f2bf(rv.w);
            }
            __syncthreads();
        }
        const int ccol = w * 16 + lr;
        f32x4 acc = {0.f, 0.f, 0.f, 0.f};
#pragma unroll
        for (int kh = 0; kh < 2; ++kh) {
            short8 a = ld8(QV, SW128(lr, (kh * 32 + lg * 8) * 2));
            short8 bb;
            if constexpr (MODE == 0)
                bb = *(const short8*)(rhb + ((size_t)n * L + c0 + ccol) * DH + kh * 32 + lg * 8);
            else
                bb = ld8(KR, SW128(ccol, (kh * 32 + lg * 8) * 2));
            acc = __builtin_amdgcn_mfma_f32_16x16x32_bf16(a, bb, acc, 0, 0, 0);
        }
#pragma unroll
        for (int r2 = 0; r2 < 4; ++r2)
            BDp[(lg * 4 + r2) * BDP_ST + c0 + ccol] = f2h(acc[r2]);
        {   // row 16 (the i+1 shift row): 4 threads per column, 16 k each
            const int col = tid >> 2, kq = (tid & 3) * 16;
            float s16 = 0.f;
#pragma unroll
            for (int kk = 0; kk < 16; kk += 8) {
                short8 qa = ld8(QV, SW128(16, (kq + kk) * 2));
                short8 ra;
                if constexpr (MODE == 0)
                    ra = *(const short8*)(rhb + ((size_t)n * L + c0 + col) * DH + kq + kk);
                else
                    ra = ld8(KR, SW128(col, (kq + kk) * 2));
#pragma unroll
                for (int e = 0; e < 8; ++e)
                    s16 = fmaf(bf2f((unsigned short)qa[e]), bf2f((unsigned short)ra[e]), s16);
            }
            s16 += __shfl_xor(s16, 1);
            s16 += __shfl_xor(s16, 2);
            if ((tid & 3) == 0) BDp[16 * BDP_ST + c0 + col] = f2h(s16);
        }
    }
    __syncthreads();   // BDp visible to all

    // ================= j-loop =================
    f32x4 pv = {0.f, 0.f, 0.f, 0.f};
    float dl[4] = {0.f, 0.f, 0.f, 0.f};
    float tmp[4][NJT];               // per-head unnormalized W (static idx)
    const int jloc = w * 16 + lr;
#pragma unroll
    for (int jt = 0; jt < NJT; ++jt) {
        const int j0 = jt * 64;
        const int gj = j0 + jloc;
        if constexpr (MODE == 1) {
            for (int idx = tid; idx < 64 * 16; idx += 256) {
                const int jr = idx >> 4, d4 = (idx & 15) * 4;
                const size_t src = ((size_t)(j0 + jr) * BATCH + b) * DM + n * DH + d4;
                float4 kv = *(const float4*)(Kg + src);
                unsigned short* p = usp(KR, SW128(jr, d4 * 2));
                p[0] = f2bf(kv.x); p[1] = f2bf(kv.y); p[2] = f2bf(kv.z); p[3] = f2bf(kv.w);
                float4 vv4 = *(const float4*)(Vg + src);
                *usp(VT, SW128(d4 + 0, jr * 2)) = f2bf(vv4.x);
                *usp(VT, SW128(d4 + 1, jr * 2)) = f2bf(vv4.y);
                *usp(VT, SW128(d4 + 2, jr * 2)) = f2bf(vv4.z);
                *usp(VT, SW128(d4 + 3, jr * 2)) = f2bf(vv4.w);
            }
            __syncthreads();
        }
        // AC
        f32x4 acc = {0.f, 0.f, 0.f, 0.f};
#pragma unroll
        for (int kh = 0; kh < 2; ++kh) {
            short8 a = ld8(QU, SW128(lr, (kh * 32 + lg * 8) * 2));
            short8 bb;
            if constexpr (MODE == 0)
                bb = *(const short8*)(Kbf + ((size_t)bn * L + gj) * DH + kh * 32 + lg * 8);
            else
                bb = ld8(KR, SW128(jloc, (kh * 32 + lg * 8) * 2));
            acc = __builtin_amdgcn_mfma_f32_16x16x32_bf16(a, bb, acc, 0, 0, 0);
        }
        const bool msk = mblk[gj] != 0;
#pragma unroll
        for (int r2 = 0; r2 < 4; ++r2) {
            const int il = lg * 4 + r2;
            const int gi = i0 + il;
            const int t = gj - gi;
            float bd = 0.f;
            if (t != 1) {
                const int c = (t <= 0) ? (L - 1 + t) : (t - 2);
                bd = h2f(BDp[(il + (t >= 1 ? 1 : 0)) * BDP_ST + c]);
            }
            float s = (acc[r2] + bd) * SCALE;
            if (msk) s = -1e9f;
            const float wgt = __expf(fminf(s, 80.f));
            dl[r2] += wgt;
            tmp[r2][jt] = wgt;
            *usp(Wt, SW128(il, jloc * 2)) = f2bf(wgt);
        }
        __syncthreads();    // Wt visible
        // PV
#pragma unroll
        for (int kh = 0; kh < 2; ++kh) {
            short8 a = ld8(Wt, SW128(lr, (kh * 32 + lg * 8) * 2));
            short8 bb;
            if constexpr (MODE == 0)
                bb = *(const short8*)(Vtb + ((size_t)bn * DH + jloc) * L + j0 + kh * 32 + lg * 8);
            else
                bb = ld8(VT, SW128(jloc, (kh * 32 + lg * 8) * 2));
            pv = __builtin_amdgcn_mfma_f32_16x16x32_bf16(a, bb, pv, 0, 0, 0);
        }
        __syncthreads();    // Wt reusable next jt
    }

    // ---- denominators ----
#pragma unroll
    for (int r2 = 0; r2 < 4; ++r2) {
        float d = dl[r2];
        d += __shfl_xor(d, 1); d += __shfl_xor(d, 2);
        d += __shfl_xor(d, 4); d += __shfl_xor(d, 8);
        if (lr == 0) denomP[w][lg * 4 + r2] = d;
    }
    __syncthreads();
    if (tid < 16)
        rdenom[tid] = 1.f / (denomP[0][tid] + denomP[1][tid] + denomP[2][tid] + denomP[3][tid]);
    __syncthreads();

    // ---- out = PV / l ----
#pragma unroll
    for (int r2 = 0; r2 < 4; ++r2) {
        const int il = lg * 4 + r2;
        out[((size_t)(i0 + il) * BATCH + b) * DM + n * DH + w * 16 + lr] = pv[r2] * rdenom[il];
    }

    // ---- wm_out += W/(l*NH) via atomics (wm_out zeroed by host memset) ----
#pragma unroll
    for (int r2 = 0; r2 < 4; ++r2) {
        const int il = lg * 4 + r2;
        const float rs = rdenom[il] * (1.f / 16.f);
#pragma unroll
        for (int jt = 0; jt < NJT; ++jt) {
            atomicAdd(wm_out + ((size_t)(i0 + il) * L + jt * 64 + jloc) * BATCH + b,
                      tmp[r2][jt] * rs);
        }
    }
}

// ---------------------------------------------------------------------------
extern "C" void kernel_launch(void* const* d_in, const int* in_sizes, int n_in,
                              void* d_out, int out_size, void* d_ws, size_t ws_size,
                              hipStream_t stream)
{
    (void)in_sizes; (void)n_in; (void)out_size;
    const float* q   = (const float*)d_in[0];
    const float* K   = (const float*)d_in[1];
    const float* V   = (const float*)d_in[2];
    const unsigned char* mask = (const unsigned char*)d_in[3];
    const float* r   = (const float*)d_in[4];
    const float* u   = (const float*)d_in[5];
    const float* v   = (const float*)d_in[6];
    const float* Wr  = (const float*)d_in[7];
    const float* br  = (const float*)d_in[8];

    float* out = (float*)d_out;                    // (1024, 4, 1024)
    float* wm  = out + (size_t)L * BATCH * DM;     // (1024, 1024, 4)

    hipMemsetAsync(wm, 0, (size_t)L * L * BATCH * sizeof(float), stream);

    if (ws_size >= (size_t)18 * 1024 * 1024) {
        unsigned short* Kbf = (unsigned short*)d_ws;               // [b][n][j][d] 8MB
        unsigned short* Vtb = Kbf + (size_t)BATCH * NH * L * DH;   // [b][n][d][j] 8MB
        unsigned short* rhb = Vtb + (size_t)BATCH * NH * L * DH;   // [n][c][d]    2MB
        rh_gemm_kernel<<<dim3(16, 16), 256, 0, stream>>>(r, Wr, br, nullptr, rhb, 1);
        prepass_kernel<<<dim3(16, 4, 16), 256, 0, stream>>>(K, V, Kbf, Vtb);
        attn_kernel<0><<<dim3(64, 4, 16), 256, 0, stream>>>(q, Kbf, Vtb, mask, u, v,
                                                            rhb, out, wm);
    } else {
        float* rhf = (float*)d_ws;                                 // [c][m] f32 4MB
        rh_gemm_kernel<<<dim3(16, 16), 256, 0, stream>>>(r, Wr, br, rhf, nullptr, 0);
        attn_kernel<1><<<dim3(64, 4, 16), 256, 0, stream>>>(q, K, V, mask, u, v,
                                                            rhf, out, wm);
    }
}

// Round 5
// 356.580 us; speedup vs baseline: 15.4300x; 2.8792x over previous
//
#include <hip/hip_runtime.h>
#include <hip/hip_fp16.h>
#include <stdint.h>

// Transformer-XL relative attention, round 5: head-parallel MFMA, no atomics.
// L=qlen=klen=1024, BATCH=4, NH=16, DH=64, DM=1024.
//
// Round-5 change: wm_out atomics (round 4: 1.06 GB RMW traffic, kernel pinned
// at 1.2 TB/s) replaced by plain bf16 stores of normalized per-head weights
// into d_ws (W_ws[b*16+n][i][j], 134 MB) + a BW-bound 16-plane reduce kernel.
// Tiered on ws_size: PLAIN (>=153MB) / ATOMIC fallback (>=18.9MB) / f32 MODE1.
//
// rel_shift map (HW-verified rounds 2-4): t=j-i;
//   BD = (t==1) ? 0 : BDp[i + (t>=1)][ t<=0 ? 1023+t : t-2 ].
// MFMA frag convention (verified rounds 3-4): A/B row|col=lane&15,
// k=(lane>>4)*8+e contiguous; D col=lane&15, row=(lane>>4)*4+reg.

#define L 1024
#define BATCH 4
#define NH 16
#define DH 64
#define DM 1024
#define TI 16
#define NJT 16
#define BDP_ST 1032     // fp16 elems per BDp row
#define SCALE 0.125f

typedef __attribute__((ext_vector_type(8))) short short8;
typedef __attribute__((ext_vector_type(4))) float f32x4;

static __device__ __forceinline__ unsigned short f2bf(float f) {
    union { float f; unsigned int u; } x; x.f = f;
    return (unsigned short)((x.u + 0x7fffu + ((x.u >> 16) & 1u)) >> 16);  // RNE
}
static __device__ __forceinline__ float bf2f(unsigned short h) {
    union { unsigned int u; float f; } x; x.u = ((unsigned int)h) << 16;
    return x.f;
}
static __device__ __forceinline__ unsigned short f2h(float f) {
    __half h = __float2half(f);
    union { __half h; unsigned short s; } x; x.h = h; return x.s;
}
static __device__ __forceinline__ float h2f(unsigned short s) {
    union { __half h; unsigned short s; } x; x.s = s; return __half2float(x.h);
}
static __device__ __forceinline__ unsigned short* usp(void* base, int byteoff) {
    return (unsigned short*)((char*)base + byteoff);
}
static __device__ __forceinline__ short8 ld8(const void* base, int byteoff) {
    return *(const short8*)((const char*)base + byteoff);
}
#define SW128(row, colByte) ((((row) * 128) + (colByte)) ^ (((row) & 7) << 4))

// ---------------------------------------------------------------------------
// K1: rh[c,m] = sum_k r[c,k]*Wr[m,k] + br[m]; bf16 [n][c][d] or f32 [c][m].
// ---------------------------------------------------------------------------
__global__ __launch_bounds__(256) void rh_gemm_kernel(
    const float* __restrict__ r, const float* __restrict__ Wr,
    const float* __restrict__ br, float* __restrict__ rhf,
    unsigned short* __restrict__ rhb, int bfmode)
{
    __shared__ float As[16][65];
    __shared__ float Bs[16][65];
    const int j0 = blockIdx.x * 64;
    const int m0 = blockIdx.y * 64;
    const int tid = threadIdx.x;
    const int ty = tid >> 4, tx = tid & 15;
    float acc[4][4] = {};

    for (int k0 = 0; k0 < DM; k0 += 16) {
        const int row = tid >> 2, c4 = (tid & 3) << 2;
        float4 av = *(const float4*)(r  + (size_t)(j0 + row) * DM + k0 + c4);
        float4 bv = *(const float4*)(Wr + (size_t)(m0 + row) * DM + k0 + c4);
        __syncthreads();
        As[c4 + 0][row] = av.x; As[c4 + 1][row] = av.y;
        As[c4 + 2][row] = av.z; As[c4 + 3][row] = av.w;
        Bs[c4 + 0][row] = bv.x; Bs[c4 + 1][row] = bv.y;
        Bs[c4 + 2][row] = bv.z; Bs[c4 + 3][row] = bv.w;
        __syncthreads();
#pragma unroll
        for (int k = 0; k < 16; ++k) {
            float a[4], bb[4];
#pragma unroll
            for (int t = 0; t < 4; ++t) { a[t] = As[k][ty * 4 + t]; bb[t] = Bs[k][tx * 4 + t]; }
#pragma unroll
            for (int ii = 0; ii < 4; ++ii)
#pragma unroll
                for (int jj = 0; jj < 4; ++jj)
                    acc[ii][jj] = fmaf(a[ii], bb[jj], acc[ii][jj]);
        }
    }
#pragma unroll
    for (int ii = 0; ii < 4; ++ii) {
        const int row = j0 + ty * 4 + ii;
#pragma unroll
        for (int jj = 0; jj < 4; ++jj) {
            const int col = m0 + tx * 4 + jj;
            const float val = acc[ii][jj] + br[col];
            if (bfmode)
                rhb[(((size_t)(col >> 6)) * L + row) * DH + (col & 63)] = f2bf(val);
            else
                rhf[(size_t)row * DM + col] = val;
        }
    }
}

// ---------------------------------------------------------------------------
// Prepass: K f32[j][b][m] -> bf16 Kbf[b][n][j][d]; V -> bf16 Vtb[b][n][d][j].
// ---------------------------------------------------------------------------
__global__ __launch_bounds__(256) void prepass_kernel(
    const float* __restrict__ Kg, const float* __restrict__ Vg,
    unsigned short* __restrict__ Kbf, unsigned short* __restrict__ Vtb)
{
    __shared__ unsigned short tile[64][80];
    const int j0 = blockIdx.x * 64;
    const int b = blockIdx.y, n = blockIdx.z;
    const int bn = b * NH + n;
    const int tid = threadIdx.x;

    for (int idx = tid; idx < 64 * 16; idx += 256) {
        const int jr = idx >> 4, s4 = (idx & 15) * 4;
        const size_t src = ((size_t)(j0 + jr) * BATCH + b) * DM + n * DH + s4;
        float4 kv = *(const float4*)(Kg + src);
        ushort4 o;
        o.x = f2bf(kv.x); o.y = f2bf(kv.y); o.z = f2bf(kv.z); o.w = f2bf(kv.w);
        *(ushort4*)(Kbf + ((size_t)bn * L + j0 + jr) * DH + s4) = o;
        float4 vv4 = *(const float4*)(Vg + src);
        tile[s4 + 0][jr] = f2bf(vv4.x); tile[s4 + 1][jr] = f2bf(vv4.y);
        tile[s4 + 2][jr] = f2bf(vv4.z); tile[s4 + 3][jr] = f2bf(vv4.w);
    }
    __syncthreads();
    for (int idx = tid; idx < 64 * 8; idx += 256) {
        const int d = idx >> 3, p8 = (idx & 7) * 8;
        short8 o = *(const short8*)&tile[d][p8];
        *(short8*)(Vtb + ((size_t)bn * DH + d) * L + j0 + p8) = o;
    }
}

// ---------------------------------------------------------------------------
// wm reduce: wm_out[i,j,b] = (1/16) * sum_n W_ws[(b*16+n)][i][j]  (bf16 in)
// ---------------------------------------------------------------------------
__global__ __launch_bounds__(256) void wm_reduce_kernel(
    const unsigned short* __restrict__ W_ws, float* __restrict__ wm_out)
{
    const int gi = blockIdx.x;
    const int b  = blockIdx.y;
    const int j0 = threadIdx.x * 4;
    float acc0 = 0.f, acc1 = 0.f, acc2 = 0.f, acc3 = 0.f;
#pragma unroll
    for (int n = 0; n < NH; ++n) {
        ushort4 wv = *(const ushort4*)(W_ws + (((size_t)(b * NH + n) * L + gi) * L) + j0);
        acc0 += bf2f(wv.x); acc1 += bf2f(wv.y);
        acc2 += bf2f(wv.z); acc3 += bf2f(wv.w);
    }
    const size_t o = ((size_t)gi * L + j0) * BATCH + b;
    wm_out[o]             = acc0 * (1.f / 16.f);
    wm_out[o + BATCH]     = acc1 * (1.f / 16.f);
    wm_out[o + 2 * BATCH] = acc2 * (1.f / 16.f);
    wm_out[o + 3 * BATCH] = acc3 * (1.f / 16.f);
}

// ---------------------------------------------------------------------------
// K2: fused rel-attention, one head per block.
// MODE 0: bf16 prepassed inputs (B-frags direct from global); MODE 1: f32.
// PLAIN 1: normalized W -> bf16 plain stores into W_ws; PLAIN 0: atomics.
// ---------------------------------------------------------------------------
template<int MODE, int PLAIN>
__global__ __launch_bounds__(256, 2) void attn_kernel(
    const float* __restrict__ q,
    const void* __restrict__ Kp, const void* __restrict__ Vp,
    const unsigned char* __restrict__ maskp,
    const float* __restrict__ uu, const float* __restrict__ vvp,
    const void* __restrict__ rhp,
    float* __restrict__ out, float* __restrict__ wm_out,
    unsigned short* __restrict__ W_ws)
{
    __shared__ unsigned short QU[16 * 64];
    __shared__ unsigned short QV[17 * 64];
    __shared__ unsigned short KR[(MODE == 1) ? 64 * 64 : 8];
    __shared__ unsigned short VT[(MODE == 1) ? 64 * 64 : 8];
    __shared__ unsigned short BDp[17 * BDP_ST];
    __shared__ unsigned short Wt[16 * 64];
    __shared__ unsigned char mblk[L];
    __shared__ float denomP[4][16];
    __shared__ float rdenom[16];
    __shared__ int mflags;

    const int i0 = blockIdx.x * TI;
    const int b  = blockIdx.y;
    const int n  = blockIdx.z;
    const int bn = b * NH + n;
    const int tid = threadIdx.x;
    const int w = tid >> 6, lane = tid & 63, lr = lane & 15, lg = lane >> 4;

    const unsigned short* Kbf = (const unsigned short*)Kp;
    const unsigned short* Vtb = (const unsigned short*)Vp;
    const unsigned short* rhb = (const unsigned short*)rhp;
    const float* Kg  = (const float*)Kp;
    const float* Vg  = (const float*)Vp;
    const float* rhf = (const float*)rhp;

    // ---- mask dtype detection + staging (verified round 2) ----
    if (tid == 0) mflags = 0;
    __syncthreads();
    {
        int local = 0;
        for (int ww = tid; ww < 1024; ww += 256) {
            const unsigned int word = ((const unsigned int*)maskp)[ww];
            if (word == 0x3f800000u) local |= 1;
            else if (word & 0xffffff00u) local |= 2;
        }
        if (local) atomicOr(&mflags, local);
    }
    __syncthreads();
    {
        const int mtype = (mflags & 1) ? 2 : ((mflags & 2) ? 1 : 0);
        for (int j = tid; j < L; j += 256) {
            bool mv;
            if (mtype == 2)      mv = ((const float*)maskp)[j * BATCH + b] != 0.f;
            else if (mtype == 1) mv = maskp[j * BATCH + b] != 0;
            else                 mv = ((const int*)maskp)[j * BATCH + b] != 0;
            mblk[j] = mv ? 1 : 0;
        }
    }
    // ---- stage QU (16x64), QV (17x64) bf16 swizzled ----
    for (int idx = tid; idx < 17 * 64; idx += 256) {
        const int row = idx >> 6, d = idx & 63;
        const int gi = i0 + row;
        const float qval = (gi < L) ? q[((size_t)gi * BATCH + b) * DM + n * DH + d] : 0.f;
        *usp(QV, SW128(row, d * 2)) = f2bf(qval + vvp[n * DH + d]);
        if (row < 16) *usp(QU, SW128(row, d * 2)) = f2bf(qval + uu[n * DH + d]);
    }
    __syncthreads();

    // ================= BDp build: 16 c-tiles of 64 =================
    for (int ct = 0; ct < 16; ++ct) {
        const int c0 = ct * 64;
        if constexpr (MODE == 1) {
            __syncthreads();
            for (int idx = tid; idx < 64 * 16; idx += 256) {
                const int cr = idx >> 4, d4 = (idx & 15) * 4;
                float4 rv = *(const float4*)(rhf + (size_t)(c0 + cr) * DM + n * DH + d4);
                unsigned short* p = usp(KR, SW128(cr, d4 * 2));
                p[0] = f2bf(rv.x); p[1] = f2bf(rv.y); p[2] = f2bf(rv.z); p[3] = f2bf(rv.w);
            }
            __syncthreads();
        }
        const int ccol = w * 16 + lr;
        f32x4 acc = {0.f, 0.f, 0.f, 0.f};
#pragma unroll
        for (int kh = 0; kh < 2; ++kh) {
            short8 a = ld8(QV, SW128(lr, (kh * 32 + lg * 8) * 2));
            short8 bb;
            if constexpr (MODE == 0)
                bb = *(const short8*)(rhb + ((size_t)n * L + c0 + ccol) * DH + kh * 32 + lg * 8);
            else
                bb = ld8(KR, SW128(ccol, (kh * 32 + lg * 8) * 2));
            acc = __builtin_amdgcn_mfma_f32_16x16x32_bf16(a, bb, acc, 0, 0, 0);
        }
#pragma unroll
        for (int r2 = 0; r2 < 4; ++r2)
            BDp[(lg * 4 + r2) * BDP_ST + c0 + ccol] = f2h(acc[r2]);
        {   // row 16 (the i+1 shift row): 4 threads per column, 16 k each
            const int col = tid >> 2, kq = (tid & 3) * 16;
            float s16 = 0.f;
#pragma unroll
            for (int kk = 0; kk < 16; kk += 8) {
                short8 qa = ld8(QV, SW128(16, (kq + kk) * 2));
                short8 ra;
                if constexpr (MODE == 0)
                    ra = *(const short8*)(rhb + ((size_t)n * L + c0 + col) * DH + kq + kk);
                else
                    ra = ld8(KR, SW128(col, (kq + kk) * 2));
#pragma unroll
                for (int e = 0; e < 8; ++e)
                    s16 = fmaf(bf2f((unsigned short)qa[e]), bf2f((unsigned short)ra[e]), s16);
            }
            s16 += __shfl_xor(s16, 1);
            s16 += __shfl_xor(s16, 2);
            if ((tid & 3) == 0) BDp[16 * BDP_ST + c0 + col] = f2h(s16);
        }
    }
    __syncthreads();

    // ================= j-loop =================
    f32x4 pv = {0.f, 0.f, 0.f, 0.f};
    float dl[4] = {0.f, 0.f, 0.f, 0.f};
    float tmp[4][NJT];
    const int jloc = w * 16 + lr;
#pragma unroll
    for (int jt = 0; jt < NJT; ++jt) {
        const int j0 = jt * 64;
        const int gj = j0 + jloc;
        if constexpr (MODE == 1) {
            for (int idx = tid; idx < 64 * 16; idx += 256) {
                const int jr = idx >> 4, d4 = (idx & 15) * 4;
                const size_t src = ((size_t)(j0 + jr) * BATCH + b) * DM + n * DH + d4;
                float4 kv = *(const float4*)(Kg + src);
                unsigned short* p = usp(KR, SW128(jr, d4 * 2));
                p[0] = f2bf(kv.x); p[1] = f2bf(kv.y); p[2] = f2bf(kv.z); p[3] = f2bf(kv.w);
                float4 vv4 = *(const float4*)(Vg + src);
                *usp(VT, SW128(d4 + 0, jr * 2)) = f2bf(vv4.x);
                *usp(VT, SW128(d4 + 1, jr * 2)) = f2bf(vv4.y);
                *usp(VT, SW128(d4 + 2, jr * 2)) = f2bf(vv4.z);
                *usp(VT, SW128(d4 + 3, jr * 2)) = f2bf(vv4.w);
            }
            __syncthreads();
        }
        // AC
        f32x4 acc = {0.f, 0.f, 0.f, 0.f};
#pragma unroll
        for (int kh = 0; kh < 2; ++kh) {
            short8 a = ld8(QU, SW128(lr, (kh * 32 + lg * 8) * 2));
            short8 bb;
            if constexpr (MODE == 0)
                bb = *(const short8*)(Kbf + ((size_t)bn * L + gj) * DH + kh * 32 + lg * 8);
            else
                bb = ld8(KR, SW128(jloc, (kh * 32 + lg * 8) * 2));
            acc = __builtin_amdgcn_mfma_f32_16x16x32_bf16(a, bb, acc, 0, 0, 0);
        }
        const bool msk = mblk[gj] != 0;
#pragma unroll
        for (int r2 = 0; r2 < 4; ++r2) {
            const int il = lg * 4 + r2;
            const int gi = i0 + il;
            const int t = gj - gi;
            float bd = 0.f;
            if (t != 1) {
                const int c = (t <= 0) ? (L - 1 + t) : (t - 2);
                bd = h2f(BDp[(il + (t >= 1 ? 1 : 0)) * BDP_ST + c]);
            }
            float s = (acc[r2] + bd) * SCALE;
            if (msk) s = -1e9f;
            const float wgt = __expf(fminf(s, 80.f));
            dl[r2] += wgt;
            tmp[r2][jt] = wgt;
            *usp(Wt, SW128(il, jloc * 2)) = f2bf(wgt);
        }
        __syncthreads();
        // PV
#pragma unroll
        for (int kh = 0; kh < 2; ++kh) {
            short8 a = ld8(Wt, SW128(lr, (kh * 32 + lg * 8) * 2));
            short8 bb;
            if constexpr (MODE == 0)
                bb = *(const short8*)(Vtb + ((size_t)bn * DH + jloc) * L + j0 + kh * 32 + lg * 8);
            else
                bb = ld8(VT, SW128(jloc, (kh * 32 + lg * 8) * 2));
            pv = __builtin_amdgcn_mfma_f32_16x16x32_bf16(a, bb, pv, 0, 0, 0);
        }
        __syncthreads();
    }

    // ---- denominators ----
#pragma unroll
    for (int r2 = 0; r2 < 4; ++r2) {
        float d = dl[r2];
        d += __shfl_xor(d, 1); d += __shfl_xor(d, 2);
        d += __shfl_xor(d, 4); d += __shfl_xor(d, 8);
        if (lr == 0) denomP[w][lg * 4 + r2] = d;
    }
    __syncthreads();
    if (tid < 16)
        rdenom[tid] = 1.f / (denomP[0][tid] + denomP[1][tid] + denomP[2][tid] + denomP[3][tid]);
    __syncthreads();

    // ---- out = PV / l ----
#pragma unroll
    for (int r2 = 0; r2 < 4; ++r2) {
        const int il = lg * 4 + r2;
        out[((size_t)(i0 + il) * BATCH + b) * DM + n * DH + w * 16 + lr] = pv[r2] * rdenom[il];
    }

    if constexpr (PLAIN == 1) {
        // ---- normalized weights -> W_ws[bn][gi][j], plain bf16 stores ----
#pragma unroll
        for (int r2 = 0; r2 < 4; ++r2) {
            const int il = lg * 4 + r2;
            const float rs = rdenom[il];
            const size_t rowo = ((size_t)bn * L + i0 + il) * L;
#pragma unroll
            for (int jt = 0; jt < NJT; ++jt)
                W_ws[rowo + jt * 64 + jloc] = f2bf(tmp[r2][jt] * rs);
        }
    } else {
        // ---- wm_out += W/(l*NH) via atomics (wm_out zeroed by host memset) --
#pragma unroll
        for (int r2 = 0; r2 < 4; ++r2) {
            const int il = lg * 4 + r2;
            const float rs = rdenom[il] * (1.f / 16.f);
#pragma unroll
            for (int jt = 0; jt < NJT; ++jt)
                atomicAdd(wm_out + ((size_t)(i0 + il) * L + jt * 64 + jloc) * BATCH + b,
                          tmp[r2][jt] * rs);
        }
    }
}

// ---------------------------------------------------------------------------
extern "C" void kernel_launch(void* const* d_in, const int* in_sizes, int n_in,
                              void* d_out, int out_size, void* d_ws, size_t ws_size,
                              hipStream_t stream)
{
    (void)in_sizes; (void)n_in; (void)out_size;
    const float* q   = (const float*)d_in[0];
    const float* K   = (const float*)d_in[1];
    const float* V   = (const float*)d_in[2];
    const unsigned char* mask = (const unsigned char*)d_in[3];
    const float* r   = (const float*)d_in[4];
    const float* u   = (const float*)d_in[5];
    const float* v   = (const float*)d_in[6];
    const float* Wr  = (const float*)d_in[7];
    const float* br  = (const float*)d_in[8];

    float* out = (float*)d_out;                    // (1024, 4, 1024)
    float* wm  = out + (size_t)L * BATCH * DM;     // (1024, 1024, 4)

    const size_t kvbytes = (size_t)BATCH * NH * L * DH * 2;   // 8 MB each
    const size_t rhbytes = (size_t)NH * L * DH * 2;           // 2 MB
    const size_t wmbytes = (size_t)BATCH * NH * L * L * 2;    // 134 MB

    if (ws_size >= 2 * kvbytes + rhbytes + wmbytes) {
        // -------- PLAIN path: no atomics --------
        unsigned short* Kbf = (unsigned short*)d_ws;
        unsigned short* Vtb = Kbf + kvbytes / 2;
        unsigned short* rhb = Vtb + kvbytes / 2;
        unsigned short* Wws = rhb + rhbytes / 2;
        rh_gemm_kernel<<<dim3(16, 16), 256, 0, stream>>>(r, Wr, br, nullptr, rhb, 1);
        prepass_kernel<<<dim3(16, 4, 16), 256, 0, stream>>>(K, V, Kbf, Vtb);
        attn_kernel<0, 1><<<dim3(64, 4, 16), 256, 0, stream>>>(
            q, Kbf, Vtb, mask, u, v, rhb, out, wm, Wws);
        wm_reduce_kernel<<<dim3(L, BATCH), 256, 0, stream>>>(Wws, wm);
    } else if (ws_size >= 2 * kvbytes + rhbytes) {
        // -------- ATOMIC fallback (round-4 path) --------
        hipMemsetAsync(wm, 0, (size_t)L * L * BATCH * sizeof(float), stream);
        unsigned short* Kbf = (unsigned short*)d_ws;
        unsigned short* Vtb = Kbf + kvbytes / 2;
        unsigned short* rhb = Vtb + kvbytes / 2;
        rh_gemm_kernel<<<dim3(16, 16), 256, 0, stream>>>(r, Wr, br, nullptr, rhb, 1);
        prepass_kernel<<<dim3(16, 4, 16), 256, 0, stream>>>(K, V, Kbf, Vtb);
        attn_kernel<0, 0><<<dim3(64, 4, 16), 256, 0, stream>>>(
            q, Kbf, Vtb, mask, u, v, rhb, out, wm, nullptr);
    } else {
        // -------- f32 fallback --------
        hipMemsetAsync(wm, 0, (size_t)L * L * BATCH * sizeof(float), stream);
        float* rhf = (float*)d_ws;
        rh_gemm_kernel<<<dim3(16, 16), 256, 0, stream>>>(r, Wr, br, rhf, nullptr, 0);
        attn_kernel<1, 0><<<dim3(64, 4, 16), 256, 0, stream>>>(
            q, K, V, mask, u, v, rhf, out, wm, nullptr);
    }
}

// Round 6
// 342.114 us; speedup vs baseline: 16.0824x; 1.0423x over previous
//
#include <hip/hip_runtime.h>
#include <hip/hip_fp16.h>
#include <stdint.h>

// Transformer-XL relative attention, round 6: latency attack.
// L=qlen=klen=1024, BATCH=4, NH=16, DH=64, DM=1024.
//
// Round-6 changes vs round 5 (263us attn, MfmaUtil 4%, VALUBusy 29%, occ 32%):
//  1. __launch_bounds__(256,3): 3 blocks/CU (LDS ~45KB -> 3x45=135KB fits 160K).
//  2. Wt double-buffer -> ONE barrier per j-tile (was 2). Safety: iter jt writes
//     Wt[jt&1]; reads of Wt[jt&1] from iter jt-2 ended before iter jt-1's
//     barrier, which precedes iter jt's writes.
//  3. Register prefetch (issue-early): K/V frags for jt+1 and rh frags for
//     ct+1 loaded global->reg at iteration start, consumed next iteration.
//  4. SCALE folded into staged QU/QV (x0.125 exact) -> s = acc + bd directly.
//
// rel_shift map (HW-verified rounds 2-5): t=j-i;
//   BD = (t==1) ? 0 : BDp[i + (t>=1)][ t<=0 ? 1023+t : t-2 ].
// MFMA frag convention (verified rounds 3-5): A/B row|col=lane&15,
// k=(lane>>4)*8+e contiguous; D col=lane&15, row=(lane>>4)*4+reg.

#define L 1024
#define BATCH 4
#define NH 16
#define DH 64
#define DM 1024
#define TI 16
#define NJT 16
#define BDP_ST 1032     // fp16 elems per BDp row
#define SCALE 0.125f

typedef __attribute__((ext_vector_type(8))) short short8;
typedef __attribute__((ext_vector_type(4))) float f32x4;

static __device__ __forceinline__ unsigned short f2bf(float f) {
    union { float f; unsigned int u; } x; x.f = f;
    return (unsigned short)((x.u + 0x7fffu + ((x.u >> 16) & 1u)) >> 16);  // RNE
}
static __device__ __forceinline__ float bf2f(unsigned short h) {
    union { unsigned int u; float f; } x; x.u = ((unsigned int)h) << 16;
    return x.f;
}
static __device__ __forceinline__ unsigned short f2h(float f) {
    __half h = __float2half(f);
    union { __half h; unsigned short s; } x; x.h = h; return x.s;
}
static __device__ __forceinline__ float h2f(unsigned short s) {
    union { __half h; unsigned short s; } x; x.s = s; return __half2float(x.h);
}
static __device__ __forceinline__ unsigned short* usp(void* base, int byteoff) {
    return (unsigned short*)((char*)base + byteoff);
}
static __device__ __forceinline__ short8 ld8(const void* base, int byteoff) {
    return *(const short8*)((const char*)base + byteoff);
}
#define SW128(row, colByte) ((((row) * 128) + (colByte)) ^ (((row) & 7) << 4))

// ---------------------------------------------------------------------------
// K1: rh[c,m] = sum_k r[c,k]*Wr[m,k] + br[m]; bf16 [n][c][d] or f32 [c][m].
// ---------------------------------------------------------------------------
__global__ __launch_bounds__(256) void rh_gemm_kernel(
    const float* __restrict__ r, const float* __restrict__ Wr,
    const float* __restrict__ br, float* __restrict__ rhf,
    unsigned short* __restrict__ rhb, int bfmode)
{
    __shared__ float As[16][65];
    __shared__ float Bs[16][65];
    const int j0 = blockIdx.x * 64;
    const int m0 = blockIdx.y * 64;
    const int tid = threadIdx.x;
    const int ty = tid >> 4, tx = tid & 15;
    float acc[4][4] = {};

    for (int k0 = 0; k0 < DM; k0 += 16) {
        const int row = tid >> 2, c4 = (tid & 3) << 2;
        float4 av = *(const float4*)(r  + (size_t)(j0 + row) * DM + k0 + c4);
        float4 bv = *(const float4*)(Wr + (size_t)(m0 + row) * DM + k0 + c4);
        __syncthreads();
        As[c4 + 0][row] = av.x; As[c4 + 1][row] = av.y;
        As[c4 + 2][row] = av.z; As[c4 + 3][row] = av.w;
        Bs[c4 + 0][row] = bv.x; Bs[c4 + 1][row] = bv.y;
        Bs[c4 + 2][row] = bv.z; Bs[c4 + 3][row] = bv.w;
        __syncthreads();
#pragma unroll
        for (int k = 0; k < 16; ++k) {
            float a[4], bb[4];
#pragma unroll
            for (int t = 0; t < 4; ++t) { a[t] = As[k][ty * 4 + t]; bb[t] = Bs[k][tx * 4 + t]; }
#pragma unroll
            for (int ii = 0; ii < 4; ++ii)
#pragma unroll
                for (int jj = 0; jj < 4; ++jj)
                    acc[ii][jj] = fmaf(a[ii], bb[jj], acc[ii][jj]);
        }
    }
#pragma unroll
    for (int ii = 0; ii < 4; ++ii) {
        const int row = j0 + ty * 4 + ii;
#pragma unroll
        for (int jj = 0; jj < 4; ++jj) {
            const int col = m0 + tx * 4 + jj;
            const float val = acc[ii][jj] + br[col];
            if (bfmode)
                rhb[(((size_t)(col >> 6)) * L + row) * DH + (col & 63)] = f2bf(val);
            else
                rhf[(size_t)row * DM + col] = val;
        }
    }
}

// ---------------------------------------------------------------------------
// Prepass: K f32[j][b][m] -> bf16 Kbf[b][n][j][d]; V -> bf16 Vtb[b][n][d][j].
// ---------------------------------------------------------------------------
__global__ __launch_bounds__(256) void prepass_kernel(
    const float* __restrict__ Kg, const float* __restrict__ Vg,
    unsigned short* __restrict__ Kbf, unsigned short* __restrict__ Vtb)
{
    __shared__ unsigned short tile[64][80];
    const int j0 = blockIdx.x * 64;
    const int b = blockIdx.y, n = blockIdx.z;
    const int bn = b * NH + n;
    const int tid = threadIdx.x;

    for (int idx = tid; idx < 64 * 16; idx += 256) {
        const int jr = idx >> 4, s4 = (idx & 15) * 4;
        const size_t src = ((size_t)(j0 + jr) * BATCH + b) * DM + n * DH + s4;
        float4 kv = *(const float4*)(Kg + src);
        ushort4 o;
        o.x = f2bf(kv.x); o.y = f2bf(kv.y); o.z = f2bf(kv.z); o.w = f2bf(kv.w);
        *(ushort4*)(Kbf + ((size_t)bn * L + j0 + jr) * DH + s4) = o;
        float4 vv4 = *(const float4*)(Vg + src);
        tile[s4 + 0][jr] = f2bf(vv4.x); tile[s4 + 1][jr] = f2bf(vv4.y);
        tile[s4 + 2][jr] = f2bf(vv4.z); tile[s4 + 3][jr] = f2bf(vv4.w);
    }
    __syncthreads();
    for (int idx = tid; idx < 64 * 8; idx += 256) {
        const int d = idx >> 3, p8 = (idx & 7) * 8;
        short8 o = *(const short8*)&tile[d][p8];
        *(short8*)(Vtb + ((size_t)bn * DH + d) * L + j0 + p8) = o;
    }
}

// ---------------------------------------------------------------------------
// wm reduce: wm_out[i,j,b] = (1/16) * sum_n W_ws[(b*16+n)][i][j]  (bf16 in)
// ---------------------------------------------------------------------------
__global__ __launch_bounds__(256) void wm_reduce_kernel(
    const unsigned short* __restrict__ W_ws, float* __restrict__ wm_out)
{
    const int gi = blockIdx.x;
    const int b  = blockIdx.y;
    const int j0 = threadIdx.x * 4;
    float acc0 = 0.f, acc1 = 0.f, acc2 = 0.f, acc3 = 0.f;
#pragma unroll
    for (int n = 0; n < NH; ++n) {
        ushort4 wv = *(const ushort4*)(W_ws + (((size_t)(b * NH + n) * L + gi) * L) + j0);
        acc0 += bf2f(wv.x); acc1 += bf2f(wv.y);
        acc2 += bf2f(wv.z); acc3 += bf2f(wv.w);
    }
    const size_t o = ((size_t)gi * L + j0) * BATCH + b;
    wm_out[o]             = acc0 * (1.f / 16.f);
    wm_out[o + BATCH]     = acc1 * (1.f / 16.f);
    wm_out[o + 2 * BATCH] = acc2 * (1.f / 16.f);
    wm_out[o + 3 * BATCH] = acc3 * (1.f / 16.f);
}

// ---------------------------------------------------------------------------
// K2: fused rel-attention, one head per block.
// MODE 0: bf16 prepassed inputs (B-frags direct from global); MODE 1: f32.
// PLAIN 1: normalized W -> bf16 plain stores into W_ws; PLAIN 0: atomics.
// ---------------------------------------------------------------------------
template<int MODE, int PLAIN>
__global__ __launch_bounds__(256, 3) void attn_kernel(
    const float* __restrict__ q,
    const void* __restrict__ Kp, const void* __restrict__ Vp,
    const unsigned char* __restrict__ maskp,
    const float* __restrict__ uu, const float* __restrict__ vvp,
    const void* __restrict__ rhp,
    float* __restrict__ out, float* __restrict__ wm_out,
    unsigned short* __restrict__ W_ws)
{
    __shared__ unsigned short QU[16 * 64];
    __shared__ unsigned short QV[17 * 64];
    __shared__ unsigned short KR[(MODE == 1) ? 64 * 64 : 8];
    __shared__ unsigned short VT[(MODE == 1) ? 64 * 64 : 8];
    __shared__ unsigned short BDp[17 * BDP_ST];
    __shared__ unsigned short Wt[2][16 * 64];       // double-buffered
    __shared__ unsigned char mblk[L];
    __shared__ float denomP[4][16];
    __shared__ float rdenom[16];
    __shared__ int mflags;

    const int i0 = blockIdx.x * TI;
    const int b  = blockIdx.y;
    const int n  = blockIdx.z;
    const int bn = b * NH + n;
    const int tid = threadIdx.x;
    const int w = tid >> 6, lane = tid & 63, lr = lane & 15, lg = lane >> 4;

    const unsigned short* Kbf = (const unsigned short*)Kp;
    const unsigned short* Vtb = (const unsigned short*)Vp;
    const unsigned short* rhb = (const unsigned short*)rhp;
    const float* Kg  = (const float*)Kp;
    const float* Vg  = (const float*)Vp;
    const float* rhf = (const float*)rhp;

    // ---- mask dtype detection + staging (verified round 2) ----
    if (tid == 0) mflags = 0;
    __syncthreads();
    {
        int local = 0;
        for (int ww = tid; ww < 1024; ww += 256) {
            const unsigned int word = ((const unsigned int*)maskp)[ww];
            if (word == 0x3f800000u) local |= 1;
            else if (word & 0xffffff00u) local |= 2;
        }
        if (local) atomicOr(&mflags, local);
    }
    __syncthreads();
    {
        const int mtype = (mflags & 1) ? 2 : ((mflags & 2) ? 1 : 0);
        for (int j = tid; j < L; j += 256) {
            bool mv;
            if (mtype == 2)      mv = ((const float*)maskp)[j * BATCH + b] != 0.f;
            else if (mtype == 1) mv = maskp[j * BATCH + b] != 0;
            else                 mv = ((const int*)maskp)[j * BATCH + b] != 0;
            mblk[j] = mv ? 1 : 0;
        }
    }
    // ---- stage QU (16x64), QV (17x64) bf16 swizzled, SCALE folded in ----
    for (int idx = tid; idx < 17 * 64; idx += 256) {
        const int row = idx >> 6, d = idx & 63;
        const int gi = i0 + row;
        const float qval = (gi < L) ? q[((size_t)gi * BATCH + b) * DM + n * DH + d] : 0.f;
        *usp(QV, SW128(row, d * 2)) = f2bf((qval + vvp[n * DH + d]) * SCALE);
        if (row < 16) *usp(QU, SW128(row, d * 2)) = f2bf((qval + uu[n * DH + d]) * SCALE);
    }
    __syncthreads();

    // ================= BDp build: 16 c-tiles of 64, rh-frag prefetch =======
    {
        short8 rb[2][2];
        if constexpr (MODE == 0) {
#pragma unroll
            for (int kh = 0; kh < 2; ++kh)
                rb[0][kh] = *(const short8*)(rhb + ((size_t)n * L + w * 16 + lr) * DH + kh * 32 + lg * 8);
        }
#pragma unroll
        for (int ct = 0; ct < 16; ++ct) {
            const int c0 = ct * 64;
            const int ccol = w * 16 + lr;
            if constexpr (MODE == 0) {
                if (ct + 1 < 16) {
#pragma unroll
                    for (int kh = 0; kh < 2; ++kh)
                        rb[(ct + 1) & 1][kh] = *(const short8*)(rhb + ((size_t)n * L + (ct + 1) * 64 + ccol) * DH + kh * 32 + lg * 8);
                }
            } else {
                __syncthreads();
                for (int idx = tid; idx < 64 * 16; idx += 256) {
                    const int cr = idx >> 4, d4 = (idx & 15) * 4;
                    float4 rv = *(const float4*)(rhf + (size_t)(c0 + cr) * DM + n * DH + d4);
                    unsigned short* p = usp(KR, SW128(cr, d4 * 2));
                    p[0] = f2bf(rv.x); p[1] = f2bf(rv.y); p[2] = f2bf(rv.z); p[3] = f2bf(rv.w);
                }
                __syncthreads();
            }
            f32x4 acc = {0.f, 0.f, 0.f, 0.f};
#pragma unroll
            for (int kh = 0; kh < 2; ++kh) {
                short8 a = ld8(QV, SW128(lr, (kh * 32 + lg * 8) * 2));
                short8 bb;
                if constexpr (MODE == 0) bb = rb[ct & 1][kh];
                else                     bb = ld8(KR, SW128(ccol, (kh * 32 + lg * 8) * 2));
                acc = __builtin_amdgcn_mfma_f32_16x16x32_bf16(a, bb, acc, 0, 0, 0);
            }
#pragma unroll
            for (int r2 = 0; r2 < 4; ++r2)
                BDp[(lg * 4 + r2) * BDP_ST + c0 + ccol] = f2h(acc[r2]);
            {   // row 16 (the i+1 shift row): 4 threads per column, 16 k each
                const int col = tid >> 2, kq = (tid & 3) * 16;
                float s16 = 0.f;
#pragma unroll
                for (int kk = 0; kk < 16; kk += 8) {
                    short8 qa = ld8(QV, SW128(16, (kq + kk) * 2));
                    short8 ra;
                    if constexpr (MODE == 0)
                        ra = *(const short8*)(rhb + ((size_t)n * L + c0 + col) * DH + kq + kk);
                    else
                        ra = ld8(KR, SW128(col, (kq + kk) * 2));
#pragma unroll
                    for (int e = 0; e < 8; ++e)
                        s16 = fmaf(bf2f((unsigned short)qa[e]), bf2f((unsigned short)ra[e]), s16);
                }
                s16 += __shfl_xor(s16, 1);
                s16 += __shfl_xor(s16, 2);
                if ((tid & 3) == 0) BDp[16 * BDP_ST + c0 + col] = f2h(s16);
            }
        }
    }

    // ---- preload K/V frags for jt=0 (overlaps the barrier below) ----
    const int jloc = w * 16 + lr;
    short8 kf[2][2], vf[2][2];
    if constexpr (MODE == 0) {
#pragma unroll
        for (int kh = 0; kh < 2; ++kh) {
            kf[0][kh] = *(const short8*)(Kbf + ((size_t)bn * L + jloc) * DH + kh * 32 + lg * 8);
            vf[0][kh] = *(const short8*)(Vtb + ((size_t)bn * DH + jloc) * L + kh * 32 + lg * 8);
        }
    }
    __syncthreads();   // BDp visible to all

    // ================= j-loop: ONE barrier per iteration =================
    f32x4 pv = {0.f, 0.f, 0.f, 0.f};
    float dl[4] = {0.f, 0.f, 0.f, 0.f};
    float tmp[4][NJT];
#pragma unroll
    for (int jt = 0; jt < NJT; ++jt) {
        const int j0 = jt * 64;
        const int gj = j0 + jloc;
        const int cur = jt & 1;
        if constexpr (MODE == 0) {
            if (jt + 1 < NJT) {     // issue-early prefetch for jt+1
                const int j0n = (jt + 1) * 64;
#pragma unroll
                for (int kh = 0; kh < 2; ++kh) {
                    kf[cur ^ 1][kh] = *(const short8*)(Kbf + ((size_t)bn * L + j0n + jloc) * DH + kh * 32 + lg * 8);
                    vf[cur ^ 1][kh] = *(const short8*)(Vtb + ((size_t)bn * DH + jloc) * L + j0n + kh * 32 + lg * 8);
                }
            }
        } else {
            __syncthreads();   // prior-iter KR/VT readers done
            for (int idx = tid; idx < 64 * 16; idx += 256) {
                const int jr = idx >> 4, d4 = (idx & 15) * 4;
                const size_t src = ((size_t)(j0 + jr) * BATCH + b) * DM + n * DH + d4;
                float4 kv = *(const float4*)(Kg + src);
                unsigned short* p = usp(KR, SW128(jr, d4 * 2));
                p[0] = f2bf(kv.x); p[1] = f2bf(kv.y); p[2] = f2bf(kv.z); p[3] = f2bf(kv.w);
                float4 vv4 = *(const float4*)(Vg + src);
                *usp(VT, SW128(d4 + 0, jr * 2)) = f2bf(vv4.x);
                *usp(VT, SW128(d4 + 1, jr * 2)) = f2bf(vv4.y);
                *usp(VT, SW128(d4 + 2, jr * 2)) = f2bf(vv4.z);
                *usp(VT, SW128(d4 + 3, jr * 2)) = f2bf(vv4.w);
            }
            __syncthreads();
        }
        // AC
        f32x4 acc = {0.f, 0.f, 0.f, 0.f};
#pragma unroll
        for (int kh = 0; kh < 2; ++kh) {
            short8 a = ld8(QU, SW128(lr, (kh * 32 + lg * 8) * 2));
            short8 bb;
            if constexpr (MODE == 0) bb = kf[cur][kh];
            else                     bb = ld8(KR, SW128(jloc, (kh * 32 + lg * 8) * 2));
            acc = __builtin_amdgcn_mfma_f32_16x16x32_bf16(a, bb, acc, 0, 0, 0);
        }
        const bool msk = mblk[gj] != 0;
#pragma unroll
        for (int r2 = 0; r2 < 4; ++r2) {
            const int il = lg * 4 + r2;
            const int gi = i0 + il;
            const int t = gj - gi;
            float bd = 0.f;
            if (t != 1) {
                const int c = (t <= 0) ? (L - 1 + t) : (t - 2);
                bd = h2f(BDp[(il + (t >= 1 ? 1 : 0)) * BDP_ST + c]);
            }
            float s = acc[r2] + bd;           // SCALE already folded into Q
            if (msk) s = -1e9f;
            const float wgt = __expf(fminf(s, 80.f));
            dl[r2] += wgt;
            tmp[r2][jt] = wgt;
            *usp(Wt[cur], SW128(il, jloc * 2)) = f2bf(wgt);
        }
        __syncthreads();    // Wt[cur] visible; also orders next iter's writes
        // PV
#pragma unroll
        for (int kh = 0; kh < 2; ++kh) {
            short8 a = ld8(Wt[cur], SW128(lr, (kh * 32 + lg * 8) * 2));
            short8 bb;
            if constexpr (MODE == 0) bb = vf[cur][kh];
            else                     bb = ld8(VT, SW128(jloc, (kh * 32 + lg * 8) * 2));
            pv = __builtin_amdgcn_mfma_f32_16x16x32_bf16(a, bb, pv, 0, 0, 0);
        }
    }

    // ---- denominators ----
#pragma unroll
    for (int r2 = 0; r2 < 4; ++r2) {
        float d = dl[r2];
        d += __shfl_xor(d, 1); d += __shfl_xor(d, 2);
        d += __shfl_xor(d, 4); d += __shfl_xor(d, 8);
        if (lr == 0) denomP[w][lg * 4 + r2] = d;
    }
    __syncthreads();
    if (tid < 16)
        rdenom[tid] = 1.f / (denomP[0][tid] + denomP[1][tid] + denomP[2][tid] + denomP[3][tid]);
    __syncthreads();

    // ---- out = PV / l ----
#pragma unroll
    for (int r2 = 0; r2 < 4; ++r2) {
        const int il = lg * 4 + r2;
        out[((size_t)(i0 + il) * BATCH + b) * DM + n * DH + w * 16 + lr] = pv[r2] * rdenom[il];
    }

    if constexpr (PLAIN == 1) {
        // ---- normalized weights -> W_ws[bn][gi][j], plain bf16 stores ----
#pragma unroll
        for (int r2 = 0; r2 < 4; ++r2) {
            const int il = lg * 4 + r2;
            const float rs = rdenom[il];
            const size_t rowo = ((size_t)bn * L + i0 + il) * L;
#pragma unroll
            for (int jt = 0; jt < NJT; ++jt)
                W_ws[rowo + jt * 64 + jloc] = f2bf(tmp[r2][jt] * rs);
        }
    } else {
        // ---- wm_out += W/(l*NH) via atomics (wm_out zeroed by host memset) --
#pragma unroll
        for (int r2 = 0; r2 < 4; ++r2) {
            const int il = lg * 4 + r2;
            const float rs = rdenom[il] * (1.f / 16.f);
#pragma unroll
            for (int jt = 0; jt < NJT; ++jt)
                atomicAdd(wm_out + ((size_t)(i0 + il) * L + jt * 64 + jloc) * BATCH + b,
                          tmp[r2][jt] * rs);
        }
    }
}

// ---------------------------------------------------------------------------
extern "C" void kernel_launch(void* const* d_in, const int* in_sizes, int n_in,
                              void* d_out, int out_size, void* d_ws, size_t ws_size,
                              hipStream_t stream)
{
    (void)in_sizes; (void)n_in; (void)out_size;
    const float* q   = (const float*)d_in[0];
    const float* K   = (const float*)d_in[1];
    const float* V   = (const float*)d_in[2];
    const unsigned char* mask = (const unsigned char*)d_in[3];
    const float* r   = (const float*)d_in[4];
    const float* u   = (const float*)d_in[5];
    const float* v   = (const float*)d_in[6];
    const float* Wr  = (const float*)d_in[7];
    const float* br  = (const float*)d_in[8];

    float* out = (float*)d_out;                    // (1024, 4, 1024)
    float* wm  = out + (size_t)L * BATCH * DM;     // (1024, 1024, 4)

    const size_t kvbytes = (size_t)BATCH * NH * L * DH * 2;   // 8 MB each
    const size_t rhbytes = (size_t)NH * L * DH * 2;           // 2 MB
    const size_t wmbytes = (size_t)BATCH * NH * L * L * 2;    // 134 MB

    if (ws_size >= 2 * kvbytes + rhbytes + wmbytes) {
        // -------- PLAIN path: no atomics --------
        unsigned short* Kbf = (unsigned short*)d_ws;
        unsigned short* Vtb = Kbf + kvbytes / 2;
        unsigned short* rhb = Vtb + kvbytes / 2;
        unsigned short* Wws = rhb + rhbytes / 2;
        rh_gemm_kernel<<<dim3(16, 16), 256, 0, stream>>>(r, Wr, br, nullptr, rhb, 1);
        prepass_kernel<<<dim3(16, 4, 16), 256, 0, stream>>>(K, V, Kbf, Vtb);
        attn_kernel<0, 1><<<dim3(64, 4, 16), 256, 0, stream>>>(
            q, Kbf, Vtb, mask, u, v, rhb, out, wm, Wws);
        wm_reduce_kernel<<<dim3(L, BATCH), 256, 0, stream>>>(Wws, wm);
    } else if (ws_size >= 2 * kvbytes + rhbytes) {
        // -------- ATOMIC fallback (round-4 path) --------
        hipMemsetAsync(wm, 0, (size_t)L * L * BATCH * sizeof(float), stream);
        unsigned short* Kbf = (unsigned short*)d_ws;
        unsigned short* Vtb = Kbf + kvbytes / 2;
        unsigned short* rhb = Vtb + kvbytes / 2;
        rh_gemm_kernel<<<dim3(16, 16), 256, 0, stream>>>(r, Wr, br, nullptr, rhb, 1);
        prepass_kernel<<<dim3(16, 4, 16), 256, 0, stream>>>(K, V, Kbf, Vtb);
        attn_kernel<0, 0><<<dim3(64, 4, 16), 256, 0, stream>>>(
            q, Kbf, Vtb, mask, u, v, rhb, out, wm, nullptr);
    } else {
        // -------- f32 fallback --------
        hipMemsetAsync(wm, 0, (size_t)L * L * BATCH * sizeof(float), stream);
        float* rhf = (float*)d_ws;
        rh_gemm_kernel<<<dim3(16, 16), 256, 0, stream>>>(r, Wr, br, rhf, nullptr, 0);
        attn_kernel<1, 0><<<dim3(64, 4, 16), 256, 0, stream>>>(
            q, K, V, mask, u, v, rhf, out, wm, nullptr);
    }
}

// Round 7
// 297.157 us; speedup vs baseline: 18.5156x; 1.1513x over previous
//
#include <hip/hip_runtime.h>
#include <hip/hip_fp16.h>
#include <stdint.h>

// Transformer-XL relative attention, round 7: barrier-free j-loop.
// L=qlen=klen=1024, BATCH=4, NH=16, DH=64, DM=1024.
//
// Round-7 structure (main path): one head per block, 4 waves; wave w OWNS
// j-range [w*256,(w+1)*256): computes S (AC MFMA + branchless BDp gather +
// exp2), stores W to its PRIVATE Wt LDS tile (in-wave lgkmcnt ordering only)
// and streams unnormalized bf16 W to W_ws; PV accumulates over its j-range.
// Cross-wave: only the final PV-partial + denom reduction (2 barriers).
// exp2-domain throughout: Q staged with 0.125*log2e folded in.
// rel_shift gather is branchless: BDp rows padded to 1032 with ZEROED pad;
//   addr = il*1032 + e + (e<=0 ? 1023 : 1030); e==1 lands in the zero pad.
// wm_out = reduce over heads of W_ws * rdeng (1/(16*denom)) side buffer.
//
// rel_shift map (HW-verified rounds 2-6): t=j-i;
//   BD = (t==1) ? 0 : BDp[i + (t>=1)][ t<=0 ? 1023+t : t-2 ].
// MFMA frag convention (verified rounds 3-6): A/B row|col=lane&15,
// k=(lane>>4)*8+e contiguous; D col=lane&15, row=(lane>>4)*4+reg.

#define L 1024
#define BATCH 4
#define NH 16
#define DH 64
#define DM 1024
#define TI 16
#define NJT 16
#define BDP_ST 1032
#define SCALE 0.125f
#define CS 0.18033688011112042f   // 0.125 * log2(e)

typedef __attribute__((ext_vector_type(8))) short short8;
typedef __attribute__((ext_vector_type(4))) float f32x4;

static __device__ __forceinline__ unsigned short f2bf(float f) {
    union { float f; unsigned int u; } x; x.f = f;
    return (unsigned short)((x.u + 0x7fffu + ((x.u >> 16) & 1u)) >> 16);  // RNE
}
static __device__ __forceinline__ float bf2f(unsigned short h) {
    union { unsigned int u; float f; } x; x.u = ((unsigned int)h) << 16;
    return x.f;
}
static __device__ __forceinline__ unsigned short f2h(float f) {
    __half h = __float2half(f);
    union { __half h; unsigned short s; } x; x.h = h; return x.s;
}
static __device__ __forceinline__ float h2f(unsigned short s) {
    union { __half h; unsigned short s; } x; x.s = s; return __half2float(x.h);
}
static __device__ __forceinline__ unsigned short* usp(void* base, int byteoff) {
    return (unsigned short*)((char*)base + byteoff);
}
static __device__ __forceinline__ short8 ld8(const void* base, int byteoff) {
    return *(const short8*)((const char*)base + byteoff);
}
static __device__ __forceinline__ float fexp2(float x) {
#if __has_builtin(__builtin_amdgcn_exp2f)
    return __builtin_amdgcn_exp2f(x);
#else
    return __expf(x * 0.6931471805599453f);
#endif
}
#define SW128(row, colByte) ((((row) * 128) + (colByte)) ^ (((row) & 7) << 4))

// ---------------------------------------------------------------------------
// K1a (main): rh = r @ Wr^T + br via bf16 MFMA -> rhb [n][c][d] bf16.
// Block: 64 c-rows x 64 m-cols (= one head pane per blockIdx.y). 16 k-tiles.
// ---------------------------------------------------------------------------
__global__ __launch_bounds__(256) void rh_gemm_mfma(
    const float* __restrict__ r, const float* __restrict__ Wr,
    const float* __restrict__ br, unsigned short* __restrict__ rhb)
{
    __shared__ unsigned short rT[64 * 64];   // [c][k] SW128
    __shared__ unsigned short wT[64 * 64];   // [m][k] SW128
    const int c0 = blockIdx.x * 64, m0 = blockIdx.y * 64;
    const int tid = threadIdx.x;
    const int w = tid >> 6, lane = tid & 63, lr = lane & 15, lg = lane >> 4;
    f32x4 acc[4] = {};

    for (int kt = 0; kt < 16; ++kt) {
        const int k0 = kt * 64;
        __syncthreads();
        const int row = tid >> 2, cb = (tid & 3) * 16;
#pragma unroll
        for (int q4 = 0; q4 < 4; ++q4) {
            float4 rv = *(const float4*)(r + (size_t)(c0 + row) * DM + k0 + cb + q4 * 4);
            unsigned short* p = usp(rT, SW128(row, (cb + q4 * 4) * 2));
            p[0] = f2bf(rv.x); p[1] = f2bf(rv.y); p[2] = f2bf(rv.z); p[3] = f2bf(rv.w);
            float4 wv = *(const float4*)(Wr + (size_t)(m0 + row) * DM + k0 + cb + q4 * 4);
            unsigned short* pw = usp(wT, SW128(row, (cb + q4 * 4) * 2));
            pw[0] = f2bf(wv.x); pw[1] = f2bf(wv.y); pw[2] = f2bf(wv.z); pw[3] = f2bf(wv.w);
        }
        __syncthreads();
#pragma unroll
        for (int mch = 0; mch < 4; ++mch)
#pragma unroll
            for (int kh = 0; kh < 2; ++kh) {
                short8 a  = ld8(rT, SW128(w * 16 + lr,   (kh * 32 + lg * 8) * 2));
                short8 bb = ld8(wT, SW128(mch * 16 + lr, (kh * 32 + lg * 8) * 2));
                acc[mch] = __builtin_amdgcn_mfma_f32_16x16x32_bf16(a, bb, acc[mch], 0, 0, 0);
            }
    }
#pragma unroll
    for (int mch = 0; mch < 4; ++mch)
#pragma unroll
        for (int r2 = 0; r2 < 4; ++r2) {
            const int c = c0 + w * 16 + lg * 4 + r2;
            const int d = mch * 16 + lr;
            const float val = acc[mch][r2] + br[m0 + d];
            rhb[((size_t)blockIdx.y * L + c) * DH + d] = f2bf(val);
        }
}

// ---------------------------------------------------------------------------
// K1b (fallback): f32 rh for MODE1.
// ---------------------------------------------------------------------------
__global__ __launch_bounds__(256) void rh_gemm_kernel(
    const float* __restrict__ r, const float* __restrict__ Wr,
    const float* __restrict__ br, float* __restrict__ rhf)
{
    __shared__ float As[16][65];
    __shared__ float Bs[16][65];
    const int j0 = blockIdx.x * 64;
    const int m0 = blockIdx.y * 64;
    const int tid = threadIdx.x;
    const int ty = tid >> 4, tx = tid & 15;
    float acc[4][4] = {};

    for (int k0 = 0; k0 < DM; k0 += 16) {
        const int row = tid >> 2, c4 = (tid & 3) << 2;
        float4 av = *(const float4*)(r  + (size_t)(j0 + row) * DM + k0 + c4);
        float4 bv = *(const float4*)(Wr + (size_t)(m0 + row) * DM + k0 + c4);
        __syncthreads();
        As[c4 + 0][row] = av.x; As[c4 + 1][row] = av.y;
        As[c4 + 2][row] = av.z; As[c4 + 3][row] = av.w;
        Bs[c4 + 0][row] = bv.x; Bs[c4 + 1][row] = bv.y;
        Bs[c4 + 2][row] = bv.z; Bs[c4 + 3][row] = bv.w;
        __syncthreads();
#pragma unroll
        for (int k = 0; k < 16; ++k) {
            float a[4], bb[4];
#pragma unroll
            for (int t = 0; t < 4; ++t) { a[t] = As[k][ty * 4 + t]; bb[t] = Bs[k][tx * 4 + t]; }
#pragma unroll
            for (int ii = 0; ii < 4; ++ii)
#pragma unroll
                for (int jj = 0; jj < 4; ++jj)
                    acc[ii][jj] = fmaf(a[ii], bb[jj], acc[ii][jj]);
        }
    }
#pragma unroll
    for (int ii = 0; ii < 4; ++ii) {
        const int row = j0 + ty * 4 + ii;
#pragma unroll
        for (int jj = 0; jj < 4; ++jj) {
            const int col = m0 + tx * 4 + jj;
            rhf[(size_t)row * DM + col] = acc[ii][jj] + br[col];
        }
    }
}

// ---------------------------------------------------------------------------
// Prepass: K f32[j][b][m] -> bf16 Kbf[b][n][j][d]; V -> bf16 Vtb[b][n][d][j].
// ---------------------------------------------------------------------------
__global__ __launch_bounds__(256) void prepass_kernel(
    const float* __restrict__ Kg, const float* __restrict__ Vg,
    unsigned short* __restrict__ Kbf, unsigned short* __restrict__ Vtb)
{
    __shared__ unsigned short tile[64][80];
    const int j0 = blockIdx.x * 64;
    const int b = blockIdx.y, n = blockIdx.z;
    const int bn = b * NH + n;
    const int tid = threadIdx.x;

    for (int idx = tid; idx < 64 * 16; idx += 256) {
        const int jr = idx >> 4, s4 = (idx & 15) * 4;
        const size_t src = ((size_t)(j0 + jr) * BATCH + b) * DM + n * DH + s4;
        float4 kv = *(const float4*)(Kg + src);
        ushort4 o;
        o.x = f2bf(kv.x); o.y = f2bf(kv.y); o.z = f2bf(kv.z); o.w = f2bf(kv.w);
        *(ushort4*)(Kbf + ((size_t)bn * L + j0 + jr) * DH + s4) = o;
        float4 vv4 = *(const float4*)(Vg + src);
        tile[s4 + 0][jr] = f2bf(vv4.x); tile[s4 + 1][jr] = f2bf(vv4.y);
        tile[s4 + 2][jr] = f2bf(vv4.z); tile[s4 + 3][jr] = f2bf(vv4.w);
    }
    __syncthreads();
    for (int idx = tid; idx < 64 * 8; idx += 256) {
        const int d = idx >> 3, p8 = (idx & 7) * 8;
        short8 o = *(const short8*)&tile[d][p8];
        *(short8*)(Vtb + ((size_t)bn * DH + d) * L + j0 + p8) = o;
    }
}

// ---------------------------------------------------------------------------
// wm reduce: wm_out[i,j,b] = sum_n W_ws[bn][i][j] * rdeng[bn][i]
// (rdeng already contains 1/(16*denom)).
// ---------------------------------------------------------------------------
__global__ __launch_bounds__(256) void wm_reduce_kernel(
    const unsigned short* __restrict__ W_ws, const float* __restrict__ rdeng,
    float* __restrict__ wm_out)
{
    const int gi = blockIdx.x;
    const int b  = blockIdx.y;
    const int j0 = threadIdx.x * 4;
    float a0 = 0.f, a1 = 0.f, a2 = 0.f, a3 = 0.f;
#pragma unroll
    for (int n = 0; n < NH; ++n) {
        const int bn = b * NH + n;
        const float rd = rdeng[((size_t)bn << 10) + gi];
        ushort4 wv = *(const ushort4*)(W_ws + ((size_t)bn * L + gi) * L + j0);
        a0 += bf2f(wv.x) * rd; a1 += bf2f(wv.y) * rd;
        a2 += bf2f(wv.z) * rd; a3 += bf2f(wv.w) * rd;
    }
    const size_t o = ((size_t)gi * L + j0) * BATCH + b;
    wm_out[o]             = a0;
    wm_out[o + BATCH]     = a1;
    wm_out[o + 2 * BATCH] = a2;
    wm_out[o + 3 * BATCH] = a3;
}

// ---------------------------------------------------------------------------
// K2 (main): barrier-free-j-loop fused rel-attention. One head per block.
// ---------------------------------------------------------------------------
__global__ __launch_bounds__(256, 3) void attn_fused(
    const float* __restrict__ q,
    const unsigned short* __restrict__ Kbf, const unsigned short* __restrict__ Vtb,
    const unsigned char* __restrict__ maskp,
    const float* __restrict__ uu, const float* __restrict__ vvp,
    const unsigned short* __restrict__ rhb,
    float* __restrict__ out, unsigned short* __restrict__ W_ws,
    float* __restrict__ rdeng)
{
    __shared__ __align__(16) unsigned short BDp[17 * BDP_ST];   // 35088 B
    __shared__ __align__(16) unsigned short Wt[4][2][16 * 64];  // 16384 B (also pv scratch)
    __shared__ unsigned char mblk[L];                           // 1024 B
    __shared__ float denomP[4][16];
    __shared__ float rdenom[16];
    __shared__ int mflags;

    const int i0 = blockIdx.x * TI;
    const int b  = blockIdx.y;
    const int n  = blockIdx.z;
    const int bn = b * NH + n;
    const int tid = threadIdx.x;
    const int w = tid >> 6, lane = tid & 63, lr = lane & 15, lg = lane >> 4;

    // ---- mask dtype detection (verified round 2) ----
    if (tid == 0) mflags = 0;
    __syncthreads();
    {
        int local = 0;
        for (int ww = tid; ww < 1024; ww += 256) {
            const unsigned int word = ((const unsigned int*)maskp)[ww];
            if (word == 0x3f800000u) local |= 1;
            else if (word & 0xffffff00u) local |= 2;
        }
        if (local) atomicOr(&mflags, local);
    }
    __syncthreads();
    {
        const int mtype = (mflags & 1) ? 2 : ((mflags & 2) ? 1 : 0);
        for (int j = tid; j < L; j += 256) {
            bool mv;
            if (mtype == 2)      mv = ((const float*)maskp)[j * BATCH + b] != 0.f;
            else if (mtype == 1) mv = maskp[j * BATCH + b] != 0;
            else                 mv = ((const int*)maskp)[j * BATCH + b] != 0;
            mblk[j] = mv ? 1 : 0;
        }
    }
    // zero BDp pad cols (enables branchless t==1 -> 0 gather)
    if (tid < 17 * 8) {
        const int row = tid >> 3, cp = tid & 7;
        BDp[row * BDP_ST + 1024 + cp] = 0;
    }

    // ---- stage Q fragments in REGISTERS (q+u, q+v scaled by 0.125*log2e) ----
    const float* qrow = q + ((size_t)(i0 + lr) * BATCH + b) * DM + n * DH;
    const float* urow = uu + n * DH;
    const float* vrow = vvp + n * DH;
    short8 qu_a[2], qv_a[2];
#pragma unroll
    for (int kh = 0; kh < 2; ++kh) {
        const int kb = kh * 32 + lg * 8;
        float4 qa = *(const float4*)(qrow + kb), qb = *(const float4*)(qrow + kb + 4);
        float4 ua = *(const float4*)(urow + kb), ub = *(const float4*)(urow + kb + 4);
        float4 va = *(const float4*)(vrow + kb), vb = *(const float4*)(vrow + kb + 4);
        short8 su, sv;
        su[0] = (short)f2bf((qa.x + ua.x) * CS); su[1] = (short)f2bf((qa.y + ua.y) * CS);
        su[2] = (short)f2bf((qa.z + ua.z) * CS); su[3] = (short)f2bf((qa.w + ua.w) * CS);
        su[4] = (short)f2bf((qb.x + ub.x) * CS); su[5] = (short)f2bf((qb.y + ub.y) * CS);
        su[6] = (short)f2bf((qb.z + ub.z) * CS); su[7] = (short)f2bf((qb.w + ub.w) * CS);
        sv[0] = (short)f2bf((qa.x + va.x) * CS); sv[1] = (short)f2bf((qa.y + va.y) * CS);
        sv[2] = (short)f2bf((qa.z + va.z) * CS); sv[3] = (short)f2bf((qa.w + va.w) * CS);
        sv[4] = (short)f2bf((qb.x + vb.x) * CS); sv[5] = (short)f2bf((qb.y + vb.y) * CS);
        sv[6] = (short)f2bf((qb.z + vb.z) * CS); sv[7] = (short)f2bf((qb.w + vb.w) * CS);
        qu_a[kh] = su; qv_a[kh] = sv;
    }
    // row-16 QV (the i+1 shift row) in f32 regs, 16 k-elems per thread
    float qv16[16];
    {
        const int kq = (tid & 3) * 16;
        if (i0 + 16 < L) {
            const float* q16 = q + ((size_t)(i0 + 16) * BATCH + b) * DM + n * DH;
#pragma unroll
            for (int e4 = 0; e4 < 4; ++e4) {
                float4 qa = *(const float4*)(q16 + kq + e4 * 4);
                float4 va = *(const float4*)(vrow + kq + e4 * 4);
                qv16[e4 * 4 + 0] = (qa.x + va.x) * CS; qv16[e4 * 4 + 1] = (qa.y + va.y) * CS;
                qv16[e4 * 4 + 2] = (qa.z + va.z) * CS; qv16[e4 * 4 + 3] = (qa.w + va.w) * CS;
            }
        } else {
#pragma unroll
            for (int e = 0; e < 16; ++e) qv16[e] = 0.f;
        }
    }

    // ================= BDp build (no internal barriers) =================
    {
        const unsigned short* rpane = rhb + (size_t)n * L * DH;
        const int ccol = w * 16 + lr;
        short8 rb[2][2];
#pragma unroll
        for (int kh = 0; kh < 2; ++kh)
            rb[0][kh] = *(const short8*)(rpane + (size_t)ccol * DH + kh * 32 + lg * 8);
        const int col16 = tid >> 2;          // row-16 column owner (4 thr/col)
        const int kq = (tid & 3) * 16;
#pragma unroll
        for (int ct = 0; ct < 16; ++ct) {
            const int c0 = ct * 64;
            const int cur = ct & 1;
            if (ct + 1 < 16) {
#pragma unroll
                for (int kh = 0; kh < 2; ++kh)
                    rb[cur ^ 1][kh] = *(const short8*)(rpane + (size_t)((ct + 1) * 64 + ccol) * DH + kh * 32 + lg * 8);
            }
            f32x4 acc = {0.f, 0.f, 0.f, 0.f};
#pragma unroll
            for (int kh = 0; kh < 2; ++kh)
                acc = __builtin_amdgcn_mfma_f32_16x16x32_bf16(qv_a[kh], rb[cur][kh], acc, 0, 0, 0);
#pragma unroll
            for (int r2 = 0; r2 < 4; ++r2)
                BDp[(lg * 4 + r2) * BDP_ST + c0 + ccol] = f2h(acc[r2]);
            // row 16: 4 threads per column, 16 k each
            {
                short8 ra0 = *(const short8*)(rpane + (size_t)(c0 + col16) * DH + kq);
                short8 ra1 = *(const short8*)(rpane + (size_t)(c0 + col16) * DH + kq + 8);
                float s16 = 0.f;
#pragma unroll
                for (int e = 0; e < 8; ++e) {
                    s16 = fmaf(qv16[e],     bf2f((unsigned short)ra0[e]), s16);
                    s16 = fmaf(qv16[e + 8], bf2f((unsigned short)ra1[e]), s16);
                }
                s16 += __shfl_xor(s16, 1);
                s16 += __shfl_xor(s16, 2);
                if ((tid & 3) == 0) BDp[16 * BDP_ST + c0 + col16] = f2h(s16);
            }
        }
    }
    __syncthreads();   // BDp + mblk visible to all

    // ================= j-loop: ZERO barriers =================
    const unsigned short* Kpane = Kbf + (size_t)bn * L * DH;
    const unsigned short* Vpane = Vtb + (size_t)bn * DH * L;
    const int jwbase = w * 256;
    f32x4 pv[4] = {};
    float dl[4] = {0.f, 0.f, 0.f, 0.f};
    int ilb[4];
    size_t wsrow[4];
#pragma unroll
    for (int r2 = 0; r2 < 4; ++r2) {
        ilb[r2] = (lg * 4 + r2) * BDP_ST;
        wsrow[r2] = ((size_t)bn * L + i0 + lg * 4 + r2) * L;
    }
    short8 kf[2][2];
#pragma unroll
    for (int kh = 0; kh < 2; ++kh)
        kf[0][kh] = *(const short8*)(Kpane + (size_t)(jwbase + lr) * DH + kh * 32 + lg * 8);

#pragma unroll 1
    for (int sub = 0; sub < 4; ++sub) {
        const int jbase = jwbase + sub * 64;
        unsigned short* WtW = &Wt[w][sub & 1][0];
        // V fragments for this subtile (issued early, consumed after S phase)
        short8 vfr[8];
#pragma unroll
        for (int dch = 0; dch < 4; ++dch)
#pragma unroll
            for (int kh = 0; kh < 2; ++kh)
                vfr[dch * 2 + kh] = *(const short8*)(Vpane + (size_t)(dch * 16 + lr) * L + jbase + kh * 32 + lg * 8);
        // ---- S phase: 4 chunks of 16 j-cols ----
#pragma unroll
        for (int c4 = 0; c4 < 4; ++c4) {
            const int chunk = sub * 4 + c4;
            const int cur = c4 & 1;              // (sub*4 even -> parity = c4&1)
            if (chunk + 1 < 16) {
#pragma unroll
                for (int kh = 0; kh < 2; ++kh)
                    kf[cur ^ 1][kh] = *(const short8*)(Kpane + (size_t)(jwbase + (chunk + 1) * 16 + lr) * DH + kh * 32 + lg * 8);
            }
            f32x4 acc = {0.f, 0.f, 0.f, 0.f};
#pragma unroll
            for (int kh = 0; kh < 2; ++kh)
                acc = __builtin_amdgcn_mfma_f32_16x16x32_bf16(qu_a[kh], kf[cur][kh], acc, 0, 0, 0);
            const int gj = jbase + c4 * 16 + lr;
            const float mo = mblk[gj] ? -1e9f : 0.f;
            const int ebase = gj - i0 - lg * 4;  // e for r2=0; e(r2) = ebase - r2
#pragma unroll
            for (int r2 = 0; r2 < 4; ++r2) {
                const int e = ebase - r2;
                const int addr = ilb[r2] + e + ((e <= 0) ? 1023 : 1030);
                const float bd = h2f(BDp[addr]);
                float s = fminf(acc[r2] + bd + mo, 126.f);
                const float wg = fexp2(s);
                dl[r2] += wg;
                const unsigned short wb = f2bf(wg);
                *usp(WtW, SW128(lg * 4 + r2, (c4 * 16 + lr) * 2)) = wb;
                W_ws[wsrow[r2] + gj] = wb;       // unnormalized stream-out
            }
        }
        // ---- PV phase (same wave produced WtW -> lgkmcnt ordering only) ----
#pragma unroll
        for (int dch = 0; dch < 4; ++dch)
#pragma unroll
            for (int kh = 0; kh < 2; ++kh) {
                short8 a = ld8(WtW, SW128(lr, (kh * 32 + lg * 8) * 2));
                pv[dch] = __builtin_amdgcn_mfma_f32_16x16x32_bf16(a, vfr[dch * 2 + kh], pv[dch], 0, 0, 0);
            }
    }

    // ---- denom partials + PV partials to LDS (own region; reuse Wt) ----
#pragma unroll
    for (int r2 = 0; r2 < 4; ++r2) {
        float d = dl[r2];
        d += __shfl_xor(d, 1); d += __shfl_xor(d, 2);
        d += __shfl_xor(d, 4); d += __shfl_xor(d, 8);
        if (lr == 0) denomP[w][lg * 4 + r2] = d;
    }
    {
        float* pvw = (float*)&Wt[w][0][0];       // 1024 f32 per wave
#pragma unroll
        for (int dch = 0; dch < 4; ++dch)
#pragma unroll
            for (int r2 = 0; r2 < 4; ++r2)
                pvw[(lg * 4 + r2) * 64 + dch * 16 + lr] = pv[dch][r2];
    }
    __syncthreads();
    if (tid < 16) {
        const float dn = denomP[0][tid] + denomP[1][tid] + denomP[2][tid] + denomP[3][tid];
        rdenom[tid] = 1.f / dn;
        rdeng[((size_t)bn << 10) + i0 + tid] = 1.f / (dn * 16.f);
    }
    __syncthreads();

    // ---- out = (sum_w pv_w) * rdenom ----
    {
        const float* pvwAll = (const float*)&Wt[0][0][0];
        const int il = tid >> 4, d0 = (tid & 15) * 4;
        float4 o = *(const float4*)(pvwAll + 0 * 1024 + il * 64 + d0);
        float4 o1 = *(const float4*)(pvwAll + 1 * 1024 + il * 64 + d0);
        float4 o2 = *(const float4*)(pvwAll + 2 * 1024 + il * 64 + d0);
        float4 o3 = *(const float4*)(pvwAll + 3 * 1024 + il * 64 + d0);
        const float rs = rdenom[il];
        o.x = (o.x + o1.x + o2.x + o3.x) * rs;
        o.y = (o.y + o1.y + o2.y + o3.y) * rs;
        o.z = (o.z + o1.z + o2.z + o3.z) * rs;
        o.w = (o.w + o1.w + o2.w + o3.w) * rs;
        *(float4*)(out + ((size_t)(i0 + il) * BATCH + b) * DM + n * DH + d0) = o;
    }
}

// ---------------------------------------------------------------------------
// Legacy K2 (round-6 structure), kept for fallback paths.
// MODE 0: bf16 prepassed inputs; MODE 1: f32 inputs staged via LDS.
// Always atomic wm accumulation (PLAIN==0 semantics).
// ---------------------------------------------------------------------------
template<int MODE>
__global__ __launch_bounds__(256, 2) void attn_legacy(
    const float* __restrict__ q,
    const void* __restrict__ Kp, const void* __restrict__ Vp,
    const unsigned char* __restrict__ maskp,
    const float* __restrict__ uu, const float* __restrict__ vvp,
    const void* __restrict__ rhp,
    float* __restrict__ out, float* __restrict__ wm_out)
{
    __shared__ unsigned short QU[16 * 64];
    __shared__ unsigned short QV[17 * 64];
    __shared__ unsigned short KR[(MODE == 1) ? 64 * 64 : 8];
    __shared__ unsigned short VT[(MODE == 1) ? 64 * 64 : 8];
    __shared__ unsigned short BDp[17 * BDP_ST];
    __shared__ unsigned short Wt[2][16 * 64];
    __shared__ unsigned char mblk[L];
    __shared__ float denomP[4][16];
    __shared__ float rdenom[16];
    __shared__ int mflags;

    const int i0 = blockIdx.x * TI;
    const int b  = blockIdx.y;
    const int n  = blockIdx.z;
    const int bn = b * NH + n;
    const int tid = threadIdx.x;
    const int w = tid >> 6, lane = tid & 63, lr = lane & 15, lg = lane >> 4;

    const unsigned short* Kbf = (const unsigned short*)Kp;
    const unsigned short* Vtb = (const unsigned short*)Vp;
    const unsigned short* rhb = (const unsigned short*)rhp;
    const float* Kg  = (const float*)Kp;
    const float* Vg  = (const float*)Vp;
    const float* rhf = (const float*)rhp;

    if (tid == 0) mflags = 0;
    __syncthreads();
    {
        int local = 0;
        for (int ww = tid; ww < 1024; ww += 256) {
            const unsigned int word = ((const unsigned int*)maskp)[ww];
            if (word == 0x3f800000u) local |= 1;
            else if (word & 0xffffff00u) local |= 2;
        }
        if (local) atomicOr(&mflags, local);
    }
    __syncthreads();
    {
        const int mtype = (mflags & 1) ? 2 : ((mflags & 2) ? 1 : 0);
        for (int j = tid; j < L; j += 256) {
            bool mv;
            if (mtype == 2)      mv = ((const float*)maskp)[j * BATCH + b] != 0.f;
            else if (mtype == 1) mv = maskp[j * BATCH + b] != 0;
            else                 mv = ((const int*)maskp)[j * BATCH + b] != 0;
            mblk[j] = mv ? 1 : 0;
        }
    }
    for (int idx = tid; idx < 17 * 64; idx += 256) {
        const int row = idx >> 6, d = idx & 63;
        const int gi = i0 + row;
        const float qval = (gi < L) ? q[((size_t)gi * BATCH + b) * DM + n * DH + d] : 0.f;
        *usp(QV, SW128(row, d * 2)) = f2bf((qval + vvp[n * DH + d]) * SCALE);
        if (row < 16) *usp(QU, SW128(row, d * 2)) = f2bf((qval + uu[n * DH + d]) * SCALE);
    }
    __syncthreads();

    for (int ct = 0; ct < 16; ++ct) {
        const int c0 = ct * 64;
        const int ccol = w * 16 + lr;
        if constexpr (MODE == 1) {
            __syncthreads();
            for (int idx = tid; idx < 64 * 16; idx += 256) {
                const int cr = idx >> 4, d4 = (idx & 15) * 4;
                float4 rv = *(const float4*)(rhf + (size_t)(c0 + cr) * DM + n * DH + d4);
                unsigned short* p = usp(KR, SW128(cr, d4 * 2));
                p[0] = f2bf(rv.x); p[1] = f2bf(rv.y); p[2] = f2bf(rv.z); p[3] = f2bf(rv.w);
            }
            __syncthreads();
        }
        f32x4 acc = {0.f, 0.f, 0.f, 0.f};
#pragma unroll
        for (int kh = 0; kh < 2; ++kh) {
            short8 a = ld8(QV, SW128(lr, (kh * 32 + lg * 8) * 2));
            short8 bb;
            if constexpr (MODE == 0)
                bb = *(const short8*)(rhb + ((size_t)n * L + c0 + ccol) * DH + kh * 32 + lg * 8);
            else
                bb = ld8(KR, SW128(ccol, (kh * 32 + lg * 8) * 2));
            acc = __builtin_amdgcn_mfma_f32_16x16x32_bf16(a, bb, acc, 0, 0, 0);
        }
#pragma unroll
        for (int r2 = 0; r2 < 4; ++r2)
            BDp[(lg * 4 + r2) * BDP_ST + c0 + ccol] = f2h(acc[r2]);
        {
            const int col = tid >> 2, kq = (tid & 3) * 16;
            float s16 = 0.f;
#pragma unroll
            for (int kk = 0; kk < 16; kk += 8) {
                short8 qa = ld8(QV, SW128(16, (kq + kk) * 2));
                short8 ra;
                if constexpr (MODE == 0)
                    ra = *(const short8*)(rhb + ((size_t)n * L + c0 + col) * DH + kq + kk);
                else
                    ra = ld8(KR, SW128(col, (kq + kk) * 2));
#pragma unroll
                for (int e = 0; e < 8; ++e)
                    s16 = fmaf(bf2f((unsigned short)qa[e]), bf2f((unsigned short)ra[e]), s16);
            }
            s16 += __shfl_xor(s16, 1);
            s16 += __shfl_xor(s16, 2);
            if ((tid & 3) == 0) BDp[16 * BDP_ST + c0 + col] = f2h(s16);
        }
    }

    const int jloc = w * 16 + lr;
    __syncthreads();

    f32x4 pv = {0.f, 0.f, 0.f, 0.f};
    float dl[4] = {0.f, 0.f, 0.f, 0.f};
    float tmp[4][NJT];
#pragma unroll
    for (int jt = 0; jt < NJT; ++jt) {
        const int j0 = jt * 64;
        const int gj = j0 + jloc;
        const int cur = jt & 1;
        if constexpr (MODE == 1) {
            __syncthreads();
            for (int idx = tid; idx < 64 * 16; idx += 256) {
                const int jr = idx >> 4, d4 = (idx & 15) * 4;
                const size_t src = ((size_t)(j0 + jr) * BATCH + b) * DM + n * DH + d4;
                float4 kv = *(const float4*)(Kg + src);
                unsigned short* p = usp(KR, SW128(jr, d4 * 2));
                p[0] = f2bf(kv.x); p[1] = f2bf(kv.y); p[2] = f2bf(kv.z); p[3] = f2bf(kv.w);
                float4 vv4 = *(const float4*)(Vg + src);
                *usp(VT, SW128(d4 + 0, jr * 2)) = f2bf(vv4.x);
                *usp(VT, SW128(d4 + 1, jr * 2)) = f2bf(vv4.y);
                *usp(VT, SW128(d4 + 2, jr * 2)) = f2bf(vv4.z);
                *usp(VT, SW128(d4 + 3, jr * 2)) = f2bf(vv4.w);
            }
            __syncthreads();
        }
        f32x4 acc = {0.f, 0.f, 0.f, 0.f};
#pragma unroll
        for (int kh = 0; kh < 2; ++kh) {
            short8 a = ld8(QU, SW128(lr, (kh * 32 + lg * 8) * 2));
            short8 bb;
            if constexpr (MODE == 0)
                bb = *(const short8*)(Kbf + ((size_t)bn * L + gj) * DH + kh * 32 + lg * 8);
            else
                bb = ld8(KR, SW128(jloc, (kh * 32 + lg * 8) * 2));
            acc = __builtin_amdgcn_mfma_f32_16x16x32_bf16(a, bb, acc, 0, 0, 0);
        }
        const bool msk = mblk[gj] != 0;
#pragma unroll
        for (int r2 = 0; r2 < 4; ++r2) {
            const int il = lg * 4 + r2;
            const int gi = i0 + il;
            const int t = gj - gi;
            float bd = 0.f;
            if (t != 1) {
                const int c = (t <= 0) ? (L - 1 + t) : (t - 2);
                bd = h2f(BDp[(il + (t >= 1 ? 1 : 0)) * BDP_ST + c]);
            }
            float s = acc[r2] + bd;
            if (msk) s = -1e9f;
            const float wgt = __expf(fminf(s, 80.f));
            dl[r2] += wgt;
            tmp[r2][jt] = wgt;
            *usp(Wt[cur], SW128(il, jloc * 2)) = f2bf(wgt);
        }
        __syncthreads();
#pragma unroll
        for (int kh = 0; kh < 2; ++kh) {
            short8 a = ld8(Wt[cur], SW128(lr, (kh * 32 + lg * 8) * 2));
            short8 bb;
            if constexpr (MODE == 0)
                bb = *(const short8*)(Vtb + ((size_t)bn * DH + jloc) * L + j0 + kh * 32 + lg * 8);
            else
                bb = ld8(VT, SW128(jloc, (kh * 32 + lg * 8) * 2));
            pv = __builtin_amdgcn_mfma_f32_16x16x32_bf16(a, bb, pv, 0, 0, 0);
        }
    }

#pragma unroll
    for (int r2 = 0; r2 < 4; ++r2) {
        float d = dl[r2];
        d += __shfl_xor(d, 1); d += __shfl_xor(d, 2);
        d += __shfl_xor(d, 4); d += __shfl_xor(d, 8);
        if (lr == 0) denomP[w][lg * 4 + r2] = d;
    }
    __syncthreads();
    if (tid < 16)
        rdenom[tid] = 1.f / (denomP[0][tid] + denomP[1][tid] + denomP[2][tid] + denomP[3][tid]);
    __syncthreads();

#pragma unroll
    for (int r2 = 0; r2 < 4; ++r2) {
        const int il = lg * 4 + r2;
        out[((size_t)(i0 + il) * BATCH + b) * DM + n * DH + w * 16 + lr] = pv[r2] * rdenom[il];
    }
#pragma unroll
    for (int r2 = 0; r2 < 4; ++r2) {
        const int il = lg * 4 + r2;
        const float rs = rdenom[il] * (1.f / 16.f);
#pragma unroll
        for (int jt = 0; jt < NJT; ++jt)
            atomicAdd(wm_out + ((size_t)(i0 + il) * L + jt * 64 + jloc) * BATCH + b,
                      tmp[r2][jt] * rs);
    }
}

// ---------------------------------------------------------------------------
extern "C" void kernel_launch(void* const* d_in, const int* in_sizes, int n_in,
                              void* d_out, int out_size, void* d_ws, size_t ws_size,
                              hipStream_t stream)
{
    (void)in_sizes; (void)n_in; (void)out_size;
    const float* q   = (const float*)d_in[0];
    const float* K   = (const float*)d_in[1];
    const float* V   = (const float*)d_in[2];
    const unsigned char* mask = (const unsigned char*)d_in[3];
    const float* r   = (const float*)d_in[4];
    const float* u   = (const float*)d_in[5];
    const float* v   = (const float*)d_in[6];
    const float* Wr  = (const float*)d_in[7];
    const float* br  = (const float*)d_in[8];

    float* out = (float*)d_out;                    // (1024, 4, 1024)
    float* wm  = out + (size_t)L * BATCH * DM;     // (1024, 1024, 4)

    const size_t kvbytes = (size_t)BATCH * NH * L * DH * 2;   // 8 MB each
    const size_t rhbytes = (size_t)NH * L * DH * 2;           // 2 MB
    const size_t wmbytes = (size_t)BATCH * NH * L * L * 2;    // 134 MB
    const size_t rdbytes = (size_t)BATCH * NH * L * 4;        // 256 KB

    if (ws_size >= 2 * kvbytes + rhbytes + wmbytes + rdbytes) {
        // -------- main path: barrier-free kernel, no atomics --------
        unsigned short* Kbf = (unsigned short*)d_ws;
        unsigned short* Vtb = Kbf + kvbytes / 2;
        unsigned short* rhb = Vtb + kvbytes / 2;
        unsigned short* Wws = rhb + rhbytes / 2;
        float* rdeng = (float*)(Wws + wmbytes / 2);
        rh_gemm_mfma<<<dim3(16, 16), 256, 0, stream>>>(r, Wr, br, rhb);
        prepass_kernel<<<dim3(16, 4, 16), 256, 0, stream>>>(K, V, Kbf, Vtb);
        attn_fused<<<dim3(64, 4, 16), 256, 0, stream>>>(
            q, Kbf, Vtb, mask, u, v, rhb, out, Wws, rdeng);
        wm_reduce_kernel<<<dim3(L, BATCH), 256, 0, stream>>>(Wws, rdeng, wm);
    } else if (ws_size >= 2 * kvbytes + rhbytes) {
        // -------- atomic fallback --------
        hipMemsetAsync(wm, 0, (size_t)L * L * BATCH * sizeof(float), stream);
        unsigned short* Kbf = (unsigned short*)d_ws;
        unsigned short* Vtb = Kbf + kvbytes / 2;
        unsigned short* rhb = Vtb + kvbytes / 2;
        rh_gemm_mfma<<<dim3(16, 16), 256, 0, stream>>>(r, Wr, br, rhb);
        prepass_kernel<<<dim3(16, 4, 16), 256, 0, stream>>>(K, V, Kbf, Vtb);
        attn_legacy<0><<<dim3(64, 4, 16), 256, 0, stream>>>(
            q, Kbf, Vtb, mask, u, v, rhb, out, wm);
    } else {
        // -------- f32 fallback --------
        hipMemsetAsync(wm, 0, (size_t)L * L * BATCH * sizeof(float), stream);
        float* rhf = (float*)d_ws;
        rh_gemm_kernel<<<dim3(16, 16), 256, 0, stream>>>(r, Wr, br, rhf);
        attn_legacy<1><<<dim3(64, 4, 16), 256, 0, stream>>>(
            q, K, V, mask, u, v, rhf, out, wm);
    }
}

// Round 8
// 286.975 us; speedup vs baseline: 19.1725x; 1.0355x over previous
//
#include <hip/hip_runtime.h>
#include <hip/hip_fp16.h>
#include <stdint.h>

// Transformer-XL relative attention, round 8: XCD-pane swizzle + depth-2
// prefetch + coalesced fragment-layout W stores.
// L=qlen=klen=1024, BATCH=4, NH=16, DH=64, DM=1024.
//
// Round-8 changes vs round 7 (243us attn, VALUBusy 25.6, occ 32.8, stall~64%):
//  1. 1-D grid 4096 with XCD-pane swizzle: pane(b,n) = (lin&7)*8 + (lin>>3)>>6,
//     i-tile = (lin>>3)&63 -> all 64 blocks of a pane on ONE XCD (L2-resident
//     K/V/rh panes, ~200cyc instead of L3 ~500cyc).
//  2. K-frag and rh-frag prefetch distance 2 (ring-2, compile-time slots).
//  3. W stream-out: ushort4 fragment-layout Wf[bn][ib][gc][lane][4] (coalesced
//     512B/wave) instead of 64x 2B scatter; wm_reduce adapted.
//
// rel_shift map (HW-verified rounds 2-7): t=j-i;
//   BD = (t==1) ? 0 : BDp[i + (t>=1)][ t<=0 ? 1023+t : t-2 ].
// MFMA frag convention (verified rounds 3-7): A/B row|col=lane&15,
// k=(lane>>4)*8+e contiguous; D col=lane&15, row=(lane>>4)*4+reg.

#define L 1024
#define BATCH 4
#define NH 16
#define DH 64
#define DM 1024
#define TI 16
#define NJT 16
#define BDP_ST 1032
#define SCALE 0.125f
#define CS 0.18033688011112042f   // 0.125 * log2(e)

typedef __attribute__((ext_vector_type(8))) short short8;
typedef __attribute__((ext_vector_type(4))) float f32x4;

static __device__ __forceinline__ unsigned short f2bf(float f) {
    union { float f; unsigned int u; } x; x.f = f;
    return (unsigned short)((x.u + 0x7fffu + ((x.u >> 16) & 1u)) >> 16);  // RNE
}
static __device__ __forceinline__ float bf2f(unsigned short h) {
    union { unsigned int u; float f; } x; x.u = ((unsigned int)h) << 16;
    return x.f;
}
static __device__ __forceinline__ unsigned short f2h(float f) {
    __half h = __float2half(f);
    union { __half h; unsigned short s; } x; x.h = h; return x.s;
}
static __device__ __forceinline__ float h2f(unsigned short s) {
    union { __half h; unsigned short s; } x; x.s = s; return __half2float(x.h);
}
static __device__ __forceinline__ unsigned short* usp(void* base, int byteoff) {
    return (unsigned short*)((char*)base + byteoff);
}
static __device__ __forceinline__ short8 ld8(const void* base, int byteoff) {
    return *(const short8*)((const char*)base + byteoff);
}
static __device__ __forceinline__ float fexp2(float x) {
#if __has_builtin(__builtin_amdgcn_exp2f)
    return __builtin_amdgcn_exp2f(x);
#else
    return __expf(x * 0.6931471805599453f);
#endif
}
#define SW128(row, colByte) ((((row) * 128) + (colByte)) ^ (((row) & 7) << 4))

// ---------------------------------------------------------------------------
// K1a (main): rh = r @ Wr^T + br via bf16 MFMA -> rhb [n][c][d] bf16.
// ---------------------------------------------------------------------------
__global__ __launch_bounds__(256) void rh_gemm_mfma(
    const float* __restrict__ r, const float* __restrict__ Wr,
    const float* __restrict__ br, unsigned short* __restrict__ rhb)
{
    __shared__ unsigned short rT[64 * 64];   // [c][k] SW128
    __shared__ unsigned short wT[64 * 64];   // [m][k] SW128
    const int c0 = blockIdx.x * 64, m0 = blockIdx.y * 64;
    const int tid = threadIdx.x;
    const int w = tid >> 6, lane = tid & 63, lr = lane & 15, lg = lane >> 4;
    f32x4 acc[4] = {};

    for (int kt = 0; kt < 16; ++kt) {
        const int k0 = kt * 64;
        __syncthreads();
        const int row = tid >> 2, cb = (tid & 3) * 16;
#pragma unroll
        for (int q4 = 0; q4 < 4; ++q4) {
            float4 rv = *(const float4*)(r + (size_t)(c0 + row) * DM + k0 + cb + q4 * 4);
            unsigned short* p = usp(rT, SW128(row, (cb + q4 * 4) * 2));
            p[0] = f2bf(rv.x); p[1] = f2bf(rv.y); p[2] = f2bf(rv.z); p[3] = f2bf(rv.w);
            float4 wv = *(const float4*)(Wr + (size_t)(m0 + row) * DM + k0 + cb + q4 * 4);
            unsigned short* pw = usp(wT, SW128(row, (cb + q4 * 4) * 2));
            pw[0] = f2bf(wv.x); pw[1] = f2bf(wv.y); pw[2] = f2bf(wv.z); pw[3] = f2bf(wv.w);
        }
        __syncthreads();
#pragma unroll
        for (int mch = 0; mch < 4; ++mch)
#pragma unroll
            for (int kh = 0; kh < 2; ++kh) {
                short8 a  = ld8(rT, SW128(w * 16 + lr,   (kh * 32 + lg * 8) * 2));
                short8 bb = ld8(wT, SW128(mch * 16 + lr, (kh * 32 + lg * 8) * 2));
                acc[mch] = __builtin_amdgcn_mfma_f32_16x16x32_bf16(a, bb, acc[mch], 0, 0, 0);
            }
    }
#pragma unroll
    for (int mch = 0; mch < 4; ++mch)
#pragma unroll
        for (int r2 = 0; r2 < 4; ++r2) {
            const int c = c0 + w * 16 + lg * 4 + r2;
            const int d = mch * 16 + lr;
            const float val = acc[mch][r2] + br[m0 + d];
            rhb[((size_t)blockIdx.y * L + c) * DH + d] = f2bf(val);
        }
}

// ---------------------------------------------------------------------------
// K1b (fallback): f32 rh for MODE1.
// ---------------------------------------------------------------------------
__global__ __launch_bounds__(256) void rh_gemm_kernel(
    const float* __restrict__ r, const float* __restrict__ Wr,
    const float* __restrict__ br, float* __restrict__ rhf)
{
    __shared__ float As[16][65];
    __shared__ float Bs[16][65];
    const int j0 = blockIdx.x * 64;
    const int m0 = blockIdx.y * 64;
    const int tid = threadIdx.x;
    const int ty = tid >> 4, tx = tid & 15;
    float acc[4][4] = {};

    for (int k0 = 0; k0 < DM; k0 += 16) {
        const int row = tid >> 2, c4 = (tid & 3) << 2;
        float4 av = *(const float4*)(r  + (size_t)(j0 + row) * DM + k0 + c4);
        float4 bv = *(const float4*)(Wr + (size_t)(m0 + row) * DM + k0 + c4);
        __syncthreads();
        As[c4 + 0][row] = av.x; As[c4 + 1][row] = av.y;
        As[c4 + 2][row] = av.z; As[c4 + 3][row] = av.w;
        Bs[c4 + 0][row] = bv.x; Bs[c4 + 1][row] = bv.y;
        Bs[c4 + 2][row] = bv.z; Bs[c4 + 3][row] = bv.w;
        __syncthreads();
#pragma unroll
        for (int k = 0; k < 16; ++k) {
            float a[4], bb[4];
#pragma unroll
            for (int t = 0; t < 4; ++t) { a[t] = As[k][ty * 4 + t]; bb[t] = Bs[k][tx * 4 + t]; }
#pragma unroll
            for (int ii = 0; ii < 4; ++ii)
#pragma unroll
                for (int jj = 0; jj < 4; ++jj)
                    acc[ii][jj] = fmaf(a[ii], bb[jj], acc[ii][jj]);
        }
    }
#pragma unroll
    for (int ii = 0; ii < 4; ++ii) {
        const int row = j0 + ty * 4 + ii;
#pragma unroll
        for (int jj = 0; jj < 4; ++jj) {
            const int col = m0 + tx * 4 + jj;
            rhf[(size_t)row * DM + col] = acc[ii][jj] + br[col];
        }
    }
}

// ---------------------------------------------------------------------------
// Prepass: K f32[j][b][m] -> bf16 Kbf[b][n][j][d]; V -> bf16 Vtb[b][n][d][j].
// ---------------------------------------------------------------------------
__global__ __launch_bounds__(256) void prepass_kernel(
    const float* __restrict__ Kg, const float* __restrict__ Vg,
    unsigned short* __restrict__ Kbf, unsigned short* __restrict__ Vtb)
{
    __shared__ unsigned short tile[64][80];
    const int j0 = blockIdx.x * 64;
    const int b = blockIdx.y, n = blockIdx.z;
    const int bn = b * NH + n;
    const int tid = threadIdx.x;

    for (int idx = tid; idx < 64 * 16; idx += 256) {
        const int jr = idx >> 4, s4 = (idx & 15) * 4;
        const size_t src = ((size_t)(j0 + jr) * BATCH + b) * DM + n * DH + s4;
        float4 kv = *(const float4*)(Kg + src);
        ushort4 o;
        o.x = f2bf(kv.x); o.y = f2bf(kv.y); o.z = f2bf(kv.z); o.w = f2bf(kv.w);
        *(ushort4*)(Kbf + ((size_t)bn * L + j0 + jr) * DH + s4) = o;
        float4 vv4 = *(const float4*)(Vg + src);
        tile[s4 + 0][jr] = f2bf(vv4.x); tile[s4 + 1][jr] = f2bf(vv4.y);
        tile[s4 + 2][jr] = f2bf(vv4.z); tile[s4 + 3][jr] = f2bf(vv4.w);
    }
    __syncthreads();
    for (int idx = tid; idx < 64 * 8; idx += 256) {
        const int d = idx >> 3, p8 = (idx & 7) * 8;
        short8 o = *(const short8*)&tile[d][p8];
        *(short8*)(Vtb + ((size_t)bn * DH + d) * L + j0 + p8) = o;
    }
}

// ---------------------------------------------------------------------------
// wm reduce (fragment layout): Wf[bn][ib][gc][lane][4] where
// (i = ib*16 + lg*4 + r2, j = gc*16 + lr), lane = lg*16+lr.
// wm_out[i,j,b] = sum_n Wf[...][r2] * rdeng[bn][i].
// Block = (ig = i>>2, b); thread covers 4 j per jj-iter, 4 i-rows per load.
// ---------------------------------------------------------------------------
__global__ __launch_bounds__(256) void wm_reduce_kernel(
    const unsigned short* __restrict__ Wf, const float* __restrict__ rdeng,
    float* __restrict__ wm_out)
{
    const int ig = blockIdx.x;           // i-group: rows ig*4 .. ig*4+3
    const int b  = blockIdx.y;
    const int ib = ig >> 2, lg = ig & 3;
    const int tid = threadIdx.x;
#pragma unroll
    for (int jj = 0; jj < 4; ++jj) {
        const int j = jj * 256 + tid;
        const int gc = j >> 4, lr = j & 15;
        float a0 = 0.f, a1 = 0.f, a2 = 0.f, a3 = 0.f;
#pragma unroll
        for (int n = 0; n < NH; ++n) {
            const int bn = b * NH + n;
            const float4 rd = *(const float4*)(rdeng + ((size_t)bn << 10) + ig * 4);
            ushort4 wv = *(const ushort4*)(Wf +
                ((((size_t)bn * 64 + ib) * 64 + gc) * 64 + lg * 16 + lr) * 4);
            a0 += bf2f(wv.x) * rd.x; a1 += bf2f(wv.y) * rd.y;
            a2 += bf2f(wv.z) * rd.z; a3 += bf2f(wv.w) * rd.w;
        }
        const size_t o = ((size_t)(ig * 4) * L + j) * BATCH + b;
        wm_out[o]                      = a0;
        wm_out[o + (size_t)L * BATCH]  = a1;
        wm_out[o + 2 * (size_t)L * BATCH] = a2;
        wm_out[o + 3 * (size_t)L * BATCH] = a3;
    }
}

// ---------------------------------------------------------------------------
// K2 (main): barrier-free j-loop, XCD-pane swizzled, depth-2 prefetch.
// ---------------------------------------------------------------------------
__global__ __launch_bounds__(256, 3) void attn_fused(
    const float* __restrict__ q,
    const unsigned short* __restrict__ Kbf, const unsigned short* __restrict__ Vtb,
    const unsigned char* __restrict__ maskp,
    const float* __restrict__ uu, const float* __restrict__ vvp,
    const unsigned short* __restrict__ rhb,
    float* __restrict__ out, unsigned short* __restrict__ W_ws,
    float* __restrict__ rdeng)
{
    __shared__ __align__(16) unsigned short BDp[17 * BDP_ST];   // 35088 B
    __shared__ __align__(16) unsigned short Wt[4][2][16 * 64];  // 16384 B (+pv scratch)
    __shared__ unsigned char mblk[L];                           // 1024 B
    __shared__ float denomP[4][16];
    __shared__ float rdenom[16];
    __shared__ int mflags;

    // ---- XCD-pane swizzle: all 64 i-tile blocks of a (b,n) pane -> one XCD --
    const int lin = blockIdx.x;
    const int xcd = lin & 7, idx = lin >> 3;
    const int ib  = idx & 63;
    const int pane = xcd * 8 + (idx >> 6);     // == bn; bijective (4096%8==0)
    const int b = pane >> 4, n = pane & 15;
    const int i0 = ib * 16;
    const int bn = pane;

    const int tid = threadIdx.x;
    const int w = tid >> 6, lane = tid & 63, lr = lane & 15, lg = lane >> 4;

    // ---- mask dtype detection (verified round 2) ----
    if (tid == 0) mflags = 0;
    __syncthreads();
    {
        int local = 0;
        for (int ww = tid; ww < 1024; ww += 256) {
            const unsigned int word = ((const unsigned int*)maskp)[ww];
            if (word == 0x3f800000u) local |= 1;
            else if (word & 0xffffff00u) local |= 2;
        }
        if (local) atomicOr(&mflags, local);
    }
    __syncthreads();
    {
        const int mtype = (mflags & 1) ? 2 : ((mflags & 2) ? 1 : 0);
        for (int j = tid; j < L; j += 256) {
            bool mv;
            if (mtype == 2)      mv = ((const float*)maskp)[j * BATCH + b] != 0.f;
            else if (mtype == 1) mv = maskp[j * BATCH + b] != 0;
            else                 mv = ((const int*)maskp)[j * BATCH + b] != 0;
            mblk[j] = mv ? 1 : 0;
        }
    }
    // zero BDp pad cols (enables branchless t==1 -> 0 gather)
    if (tid < 17 * 8) {
        const int row = tid >> 3, cp = tid & 7;
        BDp[row * BDP_ST + 1024 + cp] = 0;
    }

    // ---- stage Q fragments in REGISTERS (scaled by 0.125*log2e) ----
    const float* qrow = q + ((size_t)(i0 + lr) * BATCH + b) * DM + n * DH;
    const float* urow = uu + n * DH;
    const float* vrow = vvp + n * DH;
    short8 qu_a[2], qv_a[2];
#pragma unroll
    for (int kh = 0; kh < 2; ++kh) {
        const int kb = kh * 32 + lg * 8;
        float4 qa = *(const float4*)(qrow + kb), qb = *(const float4*)(qrow + kb + 4);
        float4 ua = *(const float4*)(urow + kb), ub = *(const float4*)(urow + kb + 4);
        float4 va = *(const float4*)(vrow + kb), vb = *(const float4*)(vrow + kb + 4);
        short8 su, sv;
        su[0] = (short)f2bf((qa.x + ua.x) * CS); su[1] = (short)f2bf((qa.y + ua.y) * CS);
        su[2] = (short)f2bf((qa.z + ua.z) * CS); su[3] = (short)f2bf((qa.w + ua.w) * CS);
        su[4] = (short)f2bf((qb.x + ub.x) * CS); su[5] = (short)f2bf((qb.y + ub.y) * CS);
        su[6] = (short)f2bf((qb.z + ub.z) * CS); su[7] = (short)f2bf((qb.w + ub.w) * CS);
        sv[0] = (short)f2bf((qa.x + va.x) * CS); sv[1] = (short)f2bf((qa.y + va.y) * CS);
        sv[2] = (short)f2bf((qa.z + va.z) * CS); sv[3] = (short)f2bf((qa.w + va.w) * CS);
        sv[4] = (short)f2bf((qb.x + vb.x) * CS); sv[5] = (short)f2bf((qb.y + vb.y) * CS);
        sv[6] = (short)f2bf((qb.z + vb.z) * CS); sv[7] = (short)f2bf((qb.w + vb.w) * CS);
        qu_a[kh] = su; qv_a[kh] = sv;
    }
    // row-16 QV (the i+1 shift row) in f32 regs, 16 k-elems per thread
    float qv16[16];
    {
        const int kq = (tid & 3) * 16;
        if (i0 + 16 < L) {
            const float* q16 = q + ((size_t)(i0 + 16) * BATCH + b) * DM + n * DH;
#pragma unroll
            for (int e4 = 0; e4 < 4; ++e4) {
                float4 qa = *(const float4*)(q16 + kq + e4 * 4);
                float4 va = *(const float4*)(vrow + kq + e4 * 4);
                qv16[e4 * 4 + 0] = (qa.x + va.x) * CS; qv16[e4 * 4 + 1] = (qa.y + va.y) * CS;
                qv16[e4 * 4 + 2] = (qa.z + va.z) * CS; qv16[e4 * 4 + 3] = (qa.w + va.w) * CS;
            }
        } else {
#pragma unroll
            for (int e = 0; e < 16; ++e) qv16[e] = 0.f;
        }
    }

    // ================= BDp build (depth-2 rh prefetch, no barriers) =========
    {
        const unsigned short* rpane = rhb + (size_t)n * L * DH;
        const int ccol = w * 16 + lr;
        short8 rb[2][2];
#pragma unroll
        for (int kh = 0; kh < 2; ++kh) {
            rb[0][kh] = *(const short8*)(rpane + (size_t)ccol * DH + kh * 32 + lg * 8);
            rb[1][kh] = *(const short8*)(rpane + (size_t)(64 + ccol) * DH + kh * 32 + lg * 8);
        }
        const int col16 = tid >> 2;          // row-16 column owner (4 thr/col)
        const int kq = (tid & 3) * 16;
#pragma unroll
        for (int ct = 0; ct < 16; ++ct) {
            const int c0 = ct * 64;
            const int cur = ct & 1;
            short8 nk0, nk1;
            if (ct + 2 < 16) {               // depth-2 prefetch into cur slot
                nk0 = *(const short8*)(rpane + (size_t)((ct + 2) * 64 + ccol) * DH + lg * 8);
                nk1 = *(const short8*)(rpane + (size_t)((ct + 2) * 64 + ccol) * DH + 32 + lg * 8);
            }
            f32x4 acc = {0.f, 0.f, 0.f, 0.f};
#pragma unroll
            for (int kh = 0; kh < 2; ++kh)
                acc = __builtin_amdgcn_mfma_f32_16x16x32_bf16(qv_a[kh], rb[cur][kh], acc, 0, 0, 0);
#pragma unroll
            for (int r2 = 0; r2 < 4; ++r2)
                BDp[(lg * 4 + r2) * BDP_ST + c0 + ccol] = f2h(acc[r2]);
            // row 16: 4 threads per column, 16 k each
            {
                short8 ra0 = *(const short8*)(rpane + (size_t)(c0 + col16) * DH + kq);
                short8 ra1 = *(const short8*)(rpane + (size_t)(c0 + col16) * DH + kq + 8);
                float s16 = 0.f;
#pragma unroll
                for (int e = 0; e < 8; ++e) {
                    s16 = fmaf(qv16[e],     bf2f((unsigned short)ra0[e]), s16);
                    s16 = fmaf(qv16[e + 8], bf2f((unsigned short)ra1[e]), s16);
                }
                s16 += __shfl_xor(s16, 1);
                s16 += __shfl_xor(s16, 2);
                if ((tid & 3) == 0) BDp[16 * BDP_ST + c0 + col16] = f2h(s16);
            }
            if (ct + 2 < 16) { rb[cur][0] = nk0; rb[cur][1] = nk1; }
        }
    }
    __syncthreads();   // BDp + mblk visible to all

    // ================= j-loop: ZERO barriers, depth-2 K prefetch ============
    const unsigned short* Kpane = Kbf + (size_t)bn * L * DH;
    const unsigned short* Vpane = Vtb + (size_t)bn * DH * L;
    const int jwbase = w * 256;
    f32x4 pv[4] = {};
    float dl[4] = {0.f, 0.f, 0.f, 0.f};
    int ilb[4];
#pragma unroll
    for (int r2 = 0; r2 < 4; ++r2) ilb[r2] = (lg * 4 + r2) * BDP_ST;

    short8 kf[2][2];
#pragma unroll
    for (int kh = 0; kh < 2; ++kh) {
        kf[0][kh] = *(const short8*)(Kpane + (size_t)(jwbase + lr) * DH + kh * 32 + lg * 8);
        kf[1][kh] = *(const short8*)(Kpane + (size_t)(jwbase + 16 + lr) * DH + kh * 32 + lg * 8);
    }

#pragma unroll 1
    for (int sub = 0; sub < 4; ++sub) {
        const int jbase = jwbase + sub * 64;
        unsigned short* WtW = &Wt[w][sub & 1][0];
        // V fragments for this subtile (issued early, consumed after S phase)
        short8 vfr[8];
#pragma unroll
        for (int dch = 0; dch < 4; ++dch)
#pragma unroll
            for (int kh = 0; kh < 2; ++kh)
                vfr[dch * 2 + kh] = *(const short8*)(Vpane + (size_t)(dch * 16 + lr) * L + jbase + kh * 32 + lg * 8);
        // ---- S phase: 4 chunks of 16 j-cols ----
#pragma unroll
        for (int c4 = 0; c4 < 4; ++c4) {
            const int chunk = sub * 4 + c4;
            const int cur = c4 & 1;          // == chunk&1 (sub*4 even)
            short8 nk0, nk1;
            if (chunk + 2 < 16) {            // depth-2 prefetch
                const int jn = jwbase + (chunk + 2) * 16 + lr;
                nk0 = *(const short8*)(Kpane + (size_t)jn * DH + lg * 8);
                nk1 = *(const short8*)(Kpane + (size_t)jn * DH + 32 + lg * 8);
            }
            f32x4 acc = {0.f, 0.f, 0.f, 0.f};
#pragma unroll
            for (int kh = 0; kh < 2; ++kh)
                acc = __builtin_amdgcn_mfma_f32_16x16x32_bf16(qu_a[kh], kf[cur][kh], acc, 0, 0, 0);
            const int gj = jbase + c4 * 16 + lr;
            const float mo = mblk[gj] ? -1e9f : 0.f;
            const int ebase = gj - i0 - lg * 4;  // e for r2=0; e(r2) = ebase - r2
            ushort4 wpack;
#pragma unroll
            for (int r2 = 0; r2 < 4; ++r2) {
                const int e = ebase - r2;
                const int addr = ilb[r2] + e + ((e <= 0) ? 1023 : 1030);
                const float bd = h2f(BDp[addr]);
                float s = fminf(acc[r2] + bd + mo, 126.f);
                const float wg = fexp2(s);
                dl[r2] += wg;
                const unsigned short wb = f2bf(wg);
                ((unsigned short*)&wpack)[r2] = wb;
                *usp(WtW, SW128(lg * 4 + r2, (c4 * 16 + lr) * 2)) = wb;
            }
            {   // coalesced fragment-layout W stream-out (512B/wave)
                const int gc = w * 16 + chunk - w * 16 + jwbase / 16 + 0;  // = w*16+chunk? see below
                // gj = gc*16 + lr with gc = (jbase + c4*16)/16 = w*16 + sub*4 + c4 = w*16+chunk... wait chunk=sub*4+c4
                const int gcc = (jbase >> 4) + c4;      // global 16-col chunk
                *(ushort4*)(W_ws + ((((size_t)bn * 64 + ib) * 64 + gcc) * 64 + lane) * 4) = wpack;
                (void)gc;
            }
            if (chunk + 2 < 16) { kf[cur][0] = nk0; kf[cur][1] = nk1; }
        }
        // ---- PV phase (same wave produced WtW -> in-wave ordering only) ----
#pragma unroll
        for (int dch = 0; dch < 4; ++dch)
#pragma unroll
            for (int kh = 0; kh < 2; ++kh) {
                short8 a = ld8(WtW, SW128(lr, (kh * 32 + lg * 8) * 2));
                pv[dch] = __builtin_amdgcn_mfma_f32_16x16x32_bf16(a, vfr[dch * 2 + kh], pv[dch], 0, 0, 0);
            }
    }

    // ---- denom partials + PV partials to LDS (own region; reuse Wt) ----
#pragma unroll
    for (int r2 = 0; r2 < 4; ++r2) {
        float d = dl[r2];
        d += __shfl_xor(d, 1); d += __shfl_xor(d, 2);
        d += __shfl_xor(d, 4); d += __shfl_xor(d, 8);
        if (lr == 0) denomP[w][lg * 4 + r2] = d;
    }
    {
        float* pvw = (float*)&Wt[w][0][0];       // 1024 f32 per wave
#pragma unroll
        for (int dch = 0; dch < 4; ++dch)
#pragma unroll
            for (int r2 = 0; r2 < 4; ++r2)
                pvw[(lg * 4 + r2) * 64 + dch * 16 + lr] = pv[dch][r2];
    }
    __syncthreads();
    if (tid < 16) {
        const float dn = denomP[0][tid] + denomP[1][tid] + denomP[2][tid] + denomP[3][tid];
        rdenom[tid] = 1.f / dn;
        rdeng[((size_t)bn << 10) + i0 + tid] = 1.f / (dn * 16.f);
    }
    __syncthreads();

    // ---- out = (sum_w pv_w) * rdenom ----
    {
        const float* pvwAll = (const float*)&Wt[0][0][0];
        const int il = tid >> 4, d0 = (tid & 15) * 4;
        float4 o  = *(const float4*)(pvwAll + 0 * 1024 + il * 64 + d0);
        float4 o1 = *(const float4*)(pvwAll + 1 * 1024 + il * 64 + d0);
        float4 o2 = *(const float4*)(pvwAll + 2 * 1024 + il * 64 + d0);
        float4 o3 = *(const float4*)(pvwAll + 3 * 1024 + il * 64 + d0);
        const float rs = rdenom[il];
        o.x = (o.x + o1.x + o2.x + o3.x) * rs;
        o.y = (o.y + o1.y + o2.y + o3.y) * rs;
        o.z = (o.z + o1.z + o2.z + o3.z) * rs;
        o.w = (o.w + o1.w + o2.w + o3.w) * rs;
        *(float4*)(out + ((size_t)(i0 + il) * BATCH + b) * DM + n * DH + d0) = o;
    }
}

// ---------------------------------------------------------------------------
// Legacy K2 (round-6 structure) for fallback paths; atomic wm accumulation.
// ---------------------------------------------------------------------------
template<int MODE>
__global__ __launch_bounds__(256, 2) void attn_legacy(
    const float* __restrict__ q,
    const void* __restrict__ Kp, const void* __restrict__ Vp,
    const unsigned char* __restrict__ maskp,
    const float* __restrict__ uu, const float* __restrict__ vvp,
    const void* __restrict__ rhp,
    float* __restrict__ out, float* __restrict__ wm_out)
{
    __shared__ unsigned short QU[16 * 64];
    __shared__ unsigned short QV[17 * 64];
    __shared__ unsigned short KR[(MODE == 1) ? 64 * 64 : 8];
    __shared__ unsigned short VT[(MODE == 1) ? 64 * 64 : 8];
    __shared__ unsigned short BDp[17 * BDP_ST];
    __shared__ unsigned short Wt[2][16 * 64];
    __shared__ unsigned char mblk[L];
    __shared__ float denomP[4][16];
    __shared__ float rdenom[16];
    __shared__ int mflags;

    const int i0 = blockIdx.x * TI;
    const int b  = blockIdx.y;
    const int n  = blockIdx.z;
    const int bn = b * NH + n;
    const int tid = threadIdx.x;
    const int w = tid >> 6, lane = tid & 63, lr = lane & 15, lg = lane >> 4;

    const unsigned short* Kbf = (const unsigned short*)Kp;
    const unsigned short* Vtb = (const unsigned short*)Vp;
    const unsigned short* rhb = (const unsigned short*)rhp;
    const float* Kg  = (const float*)Kp;
    const float* Vg  = (const float*)Vp;
    const float* rhf = (const float*)rhp;

    if (tid == 0) mflags = 0;
    __syncthreads();
    {
        int local = 0;
        for (int ww = tid; ww < 1024; ww += 256) {
            const unsigned int word = ((const unsigned int*)maskp)[ww];
            if (word == 0x3f800000u) local |= 1;
            else if (word & 0xffffff00u) local |= 2;
        }
        if (local) atomicOr(&mflags, local);
    }
    __syncthreads();
    {
        const int mtype = (mflags & 1) ? 2 : ((mflags & 2) ? 1 : 0);
        for (int j = tid; j < L; j += 256) {
            bool mv;
            if (mtype == 2)      mv = ((const float*)maskp)[j * BATCH + b] != 0.f;
            else if (mtype == 1) mv = maskp[j * BATCH + b] != 0;
            else                 mv = ((const int*)maskp)[j * BATCH + b] != 0;
            mblk[j] = mv ? 1 : 0;
        }
    }
    for (int idx = tid; idx < 17 * 64; idx += 256) {
        const int row = idx >> 6, d = idx & 63;
        const int gi = i0 + row;
        const float qval = (gi < L) ? q[((size_t)gi * BATCH + b) * DM + n * DH + d] : 0.f;
        *usp(QV, SW128(row, d * 2)) = f2bf((qval + vvp[n * DH + d]) * SCALE);
        if (row < 16) *usp(QU, SW128(row, d * 2)) = f2bf((qval + uu[n * DH + d]) * SCALE);
    }
    __syncthreads();

    for (int ct = 0; ct < 16; ++ct) {
        const int c0 = ct * 64;
        const int ccol = w * 16 + lr;
        if constexpr (MODE == 1) {
            __syncthreads();
            for (int idx = tid; idx < 64 * 16; idx += 256) {
                const int cr = idx >> 4, d4 = (idx & 15) * 4;
                float4 rv = *(const float4*)(rhf + (size_t)(c0 + cr) * DM + n * DH + d4);
                unsigned short* p = usp(KR, SW128(cr, d4 * 2));
                p[0] = f2bf(rv.x); p[1] = f2bf(rv.y); p[2] = f2bf(rv.z); p[3] = f2bf(rv.w);
            }
            __syncthreads();
        }
        f32x4 acc = {0.f, 0.f, 0.f, 0.f};
#pragma unroll
        for (int kh = 0; kh < 2; ++kh) {
            short8 a = ld8(QV, SW128(lr, (kh * 32 + lg * 8) * 2));
            short8 bb;
            if constexpr (MODE == 0)
                bb = *(const short8*)(rhb + ((size_t)n * L + c0 + ccol) * DH + kh * 32 + lg * 8);
            else
                bb = ld8(KR, SW128(ccol, (kh * 32 + lg * 8) * 2));
            acc = __builtin_amdgcn_mfma_f32_16x16x32_bf16(a, bb, acc, 0, 0, 0);
        }
#pragma unroll
        for (int r2 = 0; r2 < 4; ++r2)
            BDp[(lg * 4 + r2) * BDP_ST + c0 + ccol] = f2h(acc[r2]);
        {
            const int col = tid >> 2, kq = (tid & 3) * 16;
            float s16 = 0.f;
#pragma unroll
            for (int kk = 0; kk < 16; kk += 8) {
                short8 qa = ld8(QV, SW128(16, (kq + kk) * 2));
                short8 ra;
                if constexpr (MODE == 0)
                    ra = *(const short8*)(rhb + ((size_t)n * L + c0 + col) * DH + kq + kk);
                else
                    ra = ld8(KR, SW128(col, (kq + kk) * 2));
#pragma unroll
                for (int e = 0; e < 8; ++e)
                    s16 = fmaf(bf2f((unsigned short)qa[e]), bf2f((unsigned short)ra[e]), s16);
            }
            s16 += __shfl_xor(s16, 1);
            s16 += __shfl_xor(s16, 2);
            if ((tid & 3) == 0) BDp[16 * BDP_ST + c0 + col] = f2h(s16);
        }
    }

    const int jloc = w * 16 + lr;
    __syncthreads();

    f32x4 pv = {0.f, 0.f, 0.f, 0.f};
    float dl[4] = {0.f, 0.f, 0.f, 0.f};
    float tmp[4][NJT];
#pragma unroll
    for (int jt = 0; jt < NJT; ++jt) {
        const int j0 = jt * 64;
        const int gj = j0 + jloc;
        const int cur = jt & 1;
        if constexpr (MODE == 1) {
            __syncthreads();
            for (int idx = tid; idx < 64 * 16; idx += 256) {
                const int jr = idx >> 4, d4 = (idx & 15) * 4;
                const size_t src = ((size_t)(j0 + jr) * BATCH + b) * DM + n * DH + d4;
                float4 kv = *(const float4*)(Kg + src);
                unsigned short* p = usp(KR, SW128(jr, d4 * 2));
                p[0] = f2bf(kv.x); p[1] = f2bf(kv.y); p[2] = f2bf(kv.z); p[3] = f2bf(kv.w);
                float4 vv4 = *(const float4*)(Vg + src);
                *usp(VT, SW128(d4 + 0, jr * 2)) = f2bf(vv4.x);
                *usp(VT, SW128(d4 + 1, jr * 2)) = f2bf(vv4.y);
                *usp(VT, SW128(d4 + 2, jr * 2)) = f2bf(vv4.z);
                *usp(VT, SW128(d4 + 3, jr * 2)) = f2bf(vv4.w);
            }
            __syncthreads();
        }
        f32x4 acc = {0.f, 0.f, 0.f, 0.f};
#pragma unroll
        for (int kh = 0; kh < 2; ++kh) {
            short8 a = ld8(QU, SW128(lr, (kh * 32 + lg * 8) * 2));
            short8 bb;
            if constexpr (MODE == 0)
                bb = *(const short8*)(Kbf + ((size_t)bn * L + gj) * DH + kh * 32 + lg * 8);
            else
                bb = ld8(KR, SW128(jloc, (kh * 32 + lg * 8) * 2));
            acc = __builtin_amdgcn_mfma_f32_16x16x32_bf16(a, bb, acc, 0, 0, 0);
        }
        const bool msk = mblk[gj] != 0;
#pragma unroll
        for (int r2 = 0; r2 < 4; ++r2) {
            const int il = lg * 4 + r2;
            const int gi = i0 + il;
            const int t = gj - gi;
            float bd = 0.f;
            if (t != 1) {
                const int c = (t <= 0) ? (L - 1 + t) : (t - 2);
                bd = h2f(BDp[(il + (t >= 1 ? 1 : 0)) * BDP_ST + c]);
            }
            float s = acc[r2] + bd;
            if (msk) s = -1e9f;
            const float wgt = __expf(fminf(s, 80.f));
            dl[r2] += wgt;
            tmp[r2][jt] = wgt;
            *usp(Wt[cur], SW128(il, jloc * 2)) = f2bf(wgt);
        }
        __syncthreads();
#pragma unroll
        for (int kh = 0; kh < 2; ++kh) {
            short8 a = ld8(Wt[cur], SW128(lr, (kh * 32 + lg * 8) * 2));
            short8 bb;
            if constexpr (MODE == 0)
                bb = *(const short8*)(Vtb + ((size_t)bn * DH + jloc) * L + j0 + kh * 32 + lg * 8);
            else
                bb = ld8(VT, SW128(jloc, (kh * 32 + lg * 8) * 2));
            pv = __builtin_amdgcn_mfma_f32_16x16x32_bf16(a, bb, pv, 0, 0, 0);
        }
    }

#pragma unroll
    for (int r2 = 0; r2 < 4; ++r2) {
        float d = dl[r2];
        d += __shfl_xor(d, 1); d += __shfl_xor(d, 2);
        d += __shfl_xor(d, 4); d += __shfl_xor(d, 8);
        if (lr == 0) denomP[w][lg * 4 + r2] = d;
    }
    __syncthreads();
    if (tid < 16)
        rdenom[tid] = 1.f / (denomP[0][tid] + denomP[1][tid] + denomP[2][tid] + denomP[3][tid]);
    __syncthreads();

#pragma unroll
    for (int r2 = 0; r2 < 4; ++r2) {
        const int il = lg * 4 + r2;
        out[((size_t)(i0 + il) * BATCH + b) * DM + n * DH + w * 16 + lr] = pv[r2] * rdenom[il];
    }
#pragma unroll
    for (int r2 = 0; r2 < 4; ++r2) {
        const int il = lg * 4 + r2;
        const float rs = rdenom[il] * (1.f / 16.f);
#pragma unroll
        for (int jt = 0; jt < NJT; ++jt)
            atomicAdd(wm_out + ((size_t)(i0 + il) * L + jt * 64 + jloc) * BATCH + b,
                      tmp[r2][jt] * rs);
    }
}

// ---------------------------------------------------------------------------
extern "C" void kernel_launch(void* const* d_in, const int* in_sizes, int n_in,
                              void* d_out, int out_size, void* d_ws, size_t ws_size,
                              hipStream_t stream)
{
    (void)in_sizes; (void)n_in; (void)out_size;
    const float* q   = (const float*)d_in[0];
    const float* K   = (const float*)d_in[1];
    const float* V   = (const float*)d_in[2];
    const unsigned char* mask = (const unsigned char*)d_in[3];
    const float* r   = (const float*)d_in[4];
    const float* u   = (const float*)d_in[5];
    const float* v   = (const float*)d_in[6];
    const float* Wr  = (const float*)d_in[7];
    const float* br  = (const float*)d_in[8];

    float* out = (float*)d_out;                    // (1024, 4, 1024)
    float* wm  = out + (size_t)L * BATCH * DM;     // (1024, 1024, 4)

    const size_t kvbytes = (size_t)BATCH * NH * L * DH * 2;   // 8 MB each
    const size_t rhbytes = (size_t)NH * L * DH * 2;           // 2 MB
    const size_t wmbytes = (size_t)BATCH * NH * L * L * 2;    // 134 MB
    const size_t rdbytes = (size_t)BATCH * NH * L * 4;        // 256 KB

    if (ws_size >= 2 * kvbytes + rhbytes + wmbytes + rdbytes) {
        // -------- main path: swizzled barrier-free kernel, no atomics -------
        unsigned short* Kbf = (unsigned short*)d_ws;
        unsigned short* Vtb = Kbf + kvbytes / 2;
        unsigned short* rhb = Vtb + kvbytes / 2;
        unsigned short* Wws = rhb + rhbytes / 2;
        float* rdeng = (float*)(Wws + wmbytes / 2);
        rh_gemm_mfma<<<dim3(16, 16), 256, 0, stream>>>(r, Wr, br, rhb);
        prepass_kernel<<<dim3(16, 4, 16), 256, 0, stream>>>(K, V, Kbf, Vtb);
        attn_fused<<<dim3(4096), 256, 0, stream>>>(
            q, Kbf, Vtb, mask, u, v, rhb, out, Wws, rdeng);
        wm_reduce_kernel<<<dim3(256, BATCH), 256, 0, stream>>>(Wws, rdeng, wm);
    } else if (ws_size >= 2 * kvbytes + rhbytes) {
        // -------- atomic fallback --------
        hipMemsetAsync(wm, 0, (size_t)L * L * BATCH * sizeof(float), stream);
        unsigned short* Kbf = (unsigned short*)d_ws;
        unsigned short* Vtb = Kbf + kvbytes / 2;
        unsigned short* rhb = Vtb + kvbytes / 2;
        rh_gemm_mfma<<<dim3(16, 16), 256, 0, stream>>>(r, Wr, br, rhb);
        prepass_kernel<<<dim3(16, 4, 16), 256, 0, stream>>>(K, V, Kbf, Vtb);
        attn_legacy<0><<<dim3(64, 4, 16), 256, 0, stream>>>(
            q, Kbf, Vtb, mask, u, v, rhb, out, wm);
    } else {
        // -------- f32 fallback --------
        hipMemsetAsync(wm, 0, (size_t)L * L * BATCH * sizeof(float), stream);
        float* rhf = (float*)d_ws;
        rh_gemm_kernel<<<dim3(16, 16), 256, 0, stream>>>(r, Wr, br, rhf);
        attn_legacy<1><<<dim3(64, 4, 16), 256, 0, stream>>>(
            q, K, V, mask, u, v, rhf, out, wm);
    }
}